// Round 1
// baseline (588.194 us; speedup 1.0000x reference)
//
#include <hip/hip_runtime.h>
#include <math.h>

// Bamba-9B mixer, b=1 s=2048. Round 8: proj GEMM restructured to the 256^2
// 8-phase schedule (T2 swizzle + T3/T4 counted-vmcnt + T5 setprio).
//  - gemm_bt_8ph: 256x256 tile, BK=64, 512 thr / 8 waves (2Mx4N), 128 KiB LDS
//    double buffer, raw s_barrier + counted s_waitcnt vmcnt(6) (never 0 in the
//    main loop), setprio(1) around each 16-MFMA cluster, XOR-8 chunk swizzle
//    with pre-swizzled global source (linear global_load_lds dest).
//  - out GEMM stays on the 128^2 m97-structure kernel (only 64 tiles at 256^2
//    -> 25% CU coverage would lose more than the schedule gains).
// Everything downstream of proj unchanged from round 7.
static constexpr int kS     = 2048;
static constexpr int kHID   = 2048;
static constexpr int kI     = 4096;
static constexpr int kH     = 64;
static constexpr int kP     = 64;
static constexpr int kN     = 128;
static constexpr int kConv  = 4352;   // I + 2*G*N
static constexpr int kProj  = 8512;   // I + CONV + H
static constexpr int kChunk = 256;
static constexpr int kNC    = 8;
static constexpr float kEps = 1e-5f;

typedef __attribute__((ext_vector_type(8))) short short8;            // bf16 frag
typedef __attribute__((ext_vector_type(8))) unsigned short ushort8v;
typedef __attribute__((ext_vector_type(4))) float floatx4;

__device__ __forceinline__ float siluf(float x) {
    return x / (1.f + __expf(-x));
}
__device__ __forceinline__ unsigned short f2bf(float f) {   // RNE, finite
    unsigned int u = __float_as_uint(f);
    return (unsigned short)((u + 0x7FFFu + ((u >> 16) & 1u)) >> 16);
}
__device__ __forceinline__ float bf2f(unsigned short u) {
    return __uint_as_float((unsigned int)u << 16);
}
__device__ __forceinline__ void gll16(const void* g, void* l) {
    __builtin_amdgcn_global_load_lds(
        (const __attribute__((address_space(1))) void*)g,
        (__attribute__((address_space(3))) void*)l, 16, 0, 0);
}

// ---------- fp32 -> bf16 cast, 8 elems/thread ----------
__global__ __launch_bounds__(256)
void cast_bf16_k(const float* __restrict__ in, unsigned short* __restrict__ out)
{
    size_t i = ((size_t)blockIdx.x * 256 + threadIdx.x) * 8;
    float4 a = *(const float4*)&in[i];
    float4 b = *(const float4*)&in[i + 4];
    ushort4 u0 = {f2bf(a.x), f2bf(a.y), f2bf(a.z), f2bf(a.w)};
    ushort4 u1 = {f2bf(b.x), f2bf(b.y), f2bf(b.z), f2bf(b.w)};
    *(ushort4*)&out[i] = u0;
    *(ushort4*)&out[i + 4] = u1;
}

// ---------- 256x256-tile 8-phase bf16 NT GEMM (proj GEMM) ----------
// Requires M % 256 == 0, K % 128 == 0. N ragged (clamped loads, guarded store).
// Schedule per K-tile group (4 phases): P1 reads all 8 B-frags + 8 A k=0
// frags and stages (t+1)B1; P2 reads 8 A k=1 frags, stages (t+2)B0; P3/P4
// stage (t+2)A0/A1. Each stage overwrites a region whose last ds_read
// completed >=1 phase earlier (lgkmcnt(0) + barrier), and vmcnt(6) at each
// group end proves tile t+1 fully landed before its group starts.
#define MF16(acc_, a_, b_) \
    acc_ = __builtin_amdgcn_mfma_f32_16x16x32_bf16(a_, b_, acc_, 0, 0, 0)

#define GROUP8(LA, LB, S1, S2, S3, S4, VMTAIL)                                 \
    {                                                                          \
        short8 a0[8], a1[8], bq[4][2];                                         \
        _Pragma("unroll")                                                      \
        for (int n = 0; n < 4; ++n) {                                          \
            bq[n][0] = *(const short8*)&(LB)[boff + (n << 10) + ph0];          \
            bq[n][1] = *(const short8*)&(LB)[boff + (n << 10) + ph1];          \
        }                                                                      \
        _Pragma("unroll")                                                      \
        for (int m = 0; m < 8; ++m)                                            \
            a0[m] = *(const short8*)&(LA)[aoff + (m << 10) + ph0];             \
        S1;                                                                    \
        __builtin_amdgcn_s_barrier();                                          \
        asm volatile("s_waitcnt lgkmcnt(0)" ::: "memory");                     \
        __builtin_amdgcn_s_setprio(1);                                         \
        _Pragma("unroll")                                                      \
        for (int m = 0; m < 8; ++m) {                                          \
            MF16(acc[m][0], a0[m], bq[0][0]);                                  \
            MF16(acc[m][1], a0[m], bq[1][0]);                                  \
        }                                                                      \
        __builtin_amdgcn_s_setprio(0);                                         \
        __builtin_amdgcn_s_barrier();                                          \
        _Pragma("unroll")                                                      \
        for (int m = 0; m < 8; ++m)                                            \
            a1[m] = *(const short8*)&(LA)[aoff + (m << 10) + ph1];             \
        S2;                                                                    \
        __builtin_amdgcn_s_barrier();                                          \
        asm volatile("s_waitcnt lgkmcnt(0)" ::: "memory");                     \
        __builtin_amdgcn_s_setprio(1);                                         \
        _Pragma("unroll")                                                      \
        for (int m = 0; m < 8; ++m) {                                          \
            MF16(acc[m][2], a0[m], bq[2][0]);                                  \
            MF16(acc[m][3], a0[m], bq[3][0]);                                  \
        }                                                                      \
        __builtin_amdgcn_s_setprio(0);                                         \
        __builtin_amdgcn_s_barrier();                                          \
        S3;                                                                    \
        __builtin_amdgcn_s_barrier();                                          \
        asm volatile("s_waitcnt lgkmcnt(0)" ::: "memory");                     \
        __builtin_amdgcn_s_setprio(1);                                         \
        _Pragma("unroll")                                                      \
        for (int m = 0; m < 8; ++m) {                                          \
            MF16(acc[m][0], a1[m], bq[0][1]);                                  \
            MF16(acc[m][1], a1[m], bq[1][1]);                                  \
        }                                                                      \
        __builtin_amdgcn_s_setprio(0);                                         \
        __builtin_amdgcn_s_barrier();                                          \
        S4;                                                                    \
        __builtin_amdgcn_s_barrier();                                          \
        asm volatile("s_waitcnt lgkmcnt(0)" ::: "memory");                     \
        __builtin_amdgcn_s_setprio(1);                                         \
        _Pragma("unroll")                                                      \
        for (int m = 0; m < 8; ++m) {                                          \
            MF16(acc[m][2], a1[m], bq[2][1]);                                  \
            MF16(acc[m][3], a1[m], bq[3][1]);                                  \
        }                                                                      \
        __builtin_amdgcn_s_setprio(0);                                         \
        VMTAIL;                                                                \
        __builtin_amdgcn_s_barrier();                                          \
    }

__global__ __launch_bounds__(512)
void gemm_bt_8ph(const unsigned short* __restrict__ A,
                 const unsigned short* __restrict__ B,
                 float* __restrict__ C, int M, int N, int K)
{
    __shared__ __attribute__((aligned(16))) unsigned short lds[65536]; // 128 KiB
    const int tid = threadIdx.x;
    const int lane = tid & 63, wave = tid >> 6;
    const int quad = lane >> 4, l15 = lane & 15;
    const int wm = wave >> 2, wn = wave & 3;

    // bijective XCD swizzle (m204), then nt-major / mt-fast tile order.
    const int Mt = M >> 8, Nt = (N + 255) >> 8;
    const int nwg = Mt * Nt;
    const int q = nwg >> 3, r = nwg & 7;
    const int xcd = blockIdx.x & 7, idx = blockIdx.x >> 3;
    const int wgid = (xcd < r ? xcd * (q + 1) : r * (q + 1) + (xcd - r) * q) + idx;
    const int mt = wgid % Mt, nt = wgid / Mt;
    const int m0 = mt << 8, n0 = nt << 8;

    auto stageA = [&](int t, int hh) {
        unsigned short* lb = &lds[((t & 1) << 15) + (hh << 13)];
        const int k0 = t << 6;
#pragma unroll
        for (int i = 0; i < 2; ++i) {
            const int f = tid + (i << 9);
            const int rr = f >> 3, lc = (f & 7) ^ (rr & 7);
            gll16(&A[(size_t)(m0 + (hh << 7) + rr) * K + k0 + (lc << 3)],
                  &lb[(size_t)f << 3]);
        }
    };
    auto stageB = [&](int t, int hh) {
        unsigned short* lb = &lds[((t & 1) << 15) + 16384 + (hh << 13)];
        const int k0 = t << 6;
#pragma unroll
        for (int i = 0; i < 2; ++i) {
            const int f = tid + (i << 9);
            const int rr = f >> 3, lc = (f & 7) ^ (rr & 7);
            int gr = n0 + (hh << 7) + rr; if (gr >= N) gr = N - 1;
            gll16(&B[(size_t)gr * K + k0 + (lc << 3)], &lb[(size_t)f << 3]);
        }
    };

    floatx4 acc[8][4] = {};

    const int aoff = ((wm << 7) + l15) << 6;             // A row base (shorts)
    const int boff = ((wn << 6) + l15) << 6;             // B row base
    const int ph0 = (quad ^ (l15 & 7)) << 3;             // k=0 phys chunk
    const int ph1 = ((quad + 4) ^ (l15 & 7)) << 3;       // k=1 phys chunk

    // prologue: tile0 all 4 halves, tile1 {B0,A0,A1}; leave those 3 in flight.
    stageA(0, 0); stageA(0, 1); stageB(0, 0); stageB(0, 1);
    stageB(1, 0); stageA(1, 0); stageA(1, 1);
    asm volatile("s_waitcnt vmcnt(6)" ::: "memory");
    __builtin_amdgcn_s_barrier();

    const int NITER = K >> 7;   // tile pairs
    for (int it = 0; it < NITER; ++it) {
        const int t = it << 1;
        const bool nl = (it + 1 < NITER);
        // group A: tile t (even -> buffer 0)
        GROUP8(lds, lds + 16384,
               stageB(t + 1, 1),
               if (nl) stageB(t + 2, 0),
               if (nl) stageA(t + 2, 0),
               if (nl) stageA(t + 2, 1),
               if (nl) asm volatile("s_waitcnt vmcnt(6)" ::: "memory");
               else    asm volatile("s_waitcnt vmcnt(0)" ::: "memory"))
        // group B: tile t+1 (buffer 1)
        GROUP8(lds + 32768, lds + 49152,
               if (nl) stageB(t + 2, 1),
               if (nl) stageB(t + 3, 0),
               if (nl) stageA(t + 3, 0),
               if (nl) stageA(t + 3, 1),
               if (nl) asm volatile("s_waitcnt vmcnt(6)" ::: "memory"))
    }

#pragma unroll
    for (int m = 0; m < 8; ++m) {
        const int row = m0 + (wm << 7) + m * 16 + (quad << 2);
#pragma unroll
        for (int n = 0; n < 4; ++n) {
            const int col = n0 + (wn << 6) + n * 16 + l15;
            if (col < N) {
#pragma unroll
                for (int rr = 0; rr < 4; ++rr)
                    C[(size_t)(row + rr) * N + col] = acc[m][n][rr];
            }
        }
    }
}

// ---------- bf16 MFMA NT GEMM (128^2 m97 structure; out GEMM) ----------
__global__ __launch_bounds__(256)
void gemm_bt_bf16(const unsigned short* __restrict__ A,
                  const unsigned short* __restrict__ B,
                  float* __restrict__ C, int M, int N, int K)
{
    __shared__ unsigned short As[128 * 64];
    __shared__ unsigned short Bs[128 * 64];
    const int tid = threadIdx.x;
    const int lane = tid & 63, quad = lane >> 4, l15 = lane & 15;
    const int wave = tid >> 6;

    const int Nt = (N + 127) >> 7;
    const int mainN = Nt & ~7;
    int bi = blockIdx.x, mt, nt;
    if (bi < mainN * 16) {
        nt = ((bi >> 7) << 3) | (bi & 7);
        mt = (bi >> 3) & 15;
    } else {
        int r = bi - mainN * 16, rem = Nt - mainN;
        nt = mainN + r % rem; mt = r / rem;
    }
    const int m0 = mt * 128, n0 = nt * 128;
    const int wm = (wave & 1) * 64, wn = (wave >> 1) * 64;

    floatx4 acc[4][4] = {};

    int rowS[4], lcS[4];
#pragma unroll
    for (int i = 0; i < 4; ++i) {
        int f = tid + 256 * i;
        rowS[i] = f >> 3;
        lcS[i] = ((f & 7) ^ (rowS[i] & 7)) * 8;
    }

    for (int k0 = 0; k0 < K; k0 += 64) {
#pragma unroll
        for (int i = 0; i < 4; ++i) {
            int ra = m0 + rowS[i];
            gll16(&A[(size_t)ra * K + k0 + lcS[i]], &As[(size_t)(tid + 256 * i) * 8]);
        }
#pragma unroll
        for (int i = 0; i < 4; ++i) {
            int rb = n0 + rowS[i]; if (rb > N - 1) rb = N - 1;
            gll16(&B[(size_t)rb * K + k0 + lcS[i]], &Bs[(size_t)(tid + 256 * i) * 8]);
        }
        __syncthreads();

        short8 af[4][2], bf[4][2];
#pragma unroll
        for (int ks = 0; ks < 2; ++ks) {
            const int ph = ((ks * 4 + quad) ^ (l15 & 7)) * 8;
#pragma unroll
            for (int mi = 0; mi < 4; ++mi)
                af[mi][ks] = *(const short8*)&As[(size_t)(wm + mi * 16 + l15) * 64 + ph];
#pragma unroll
            for (int ni = 0; ni < 4; ++ni)
                bf[ni][ks] = *(const short8*)&Bs[(size_t)(wn + ni * 16 + l15) * 64 + ph];
        }
#pragma unroll
        for (int ks = 0; ks < 2; ++ks)
#pragma unroll
            for (int mi = 0; mi < 4; ++mi)
#pragma unroll
                for (int ni = 0; ni < 4; ++ni)
                    acc[mi][ni] = __builtin_amdgcn_mfma_f32_16x16x32_bf16(
                        af[mi][ks], bf[ni][ks], acc[mi][ni], 0, 0, 0);
        __syncthreads();
    }

#pragma unroll
    for (int mi = 0; mi < 4; ++mi)
#pragma unroll
        for (int ni = 0; ni < 4; ++ni) {
            int col = n0 + wn + ni * 16 + l15;
            if (col < N) {
#pragma unroll
                for (int r = 0; r < 4; ++r) {
                    int row = m0 + wm + mi * 16 + quad * 4 + r;
                    C[(size_t)row * N + col] = acc[mi][ni][r];
                }
            }
        }
}

// ---------- conv+SiLU -> bf16 consumer layouts ----------
__global__ __launch_bounds__(256)
void conv_silu2_k(const float* __restrict__ proj, const float* __restrict__ cw,
                  const float* __restrict__ cb,
                  unsigned short* __restrict__ XT, unsigned short* __restrict__ Bg,
                  unsigned short* __restrict__ Btg, unsigned short* __restrict__ Cg)
{
    __shared__ __attribute__((aligned(16))) unsigned short T[64][264];
    const int bd = blockIdx.x % 68, bt = blockIdx.x / 68;
    const int d0 = bd * 64, t0 = bt * 256;
    const int tid = threadIdx.x;
    const int dl = tid & 63;
    const int d = d0 + dl;
    const float b0 = cb[d];
    const float w0 = cw[d * 4 + 0], w1 = cw[d * 4 + 1];
    const float w2 = cw[d * 4 + 2], w3 = cw[d * 4 + 3];
    for (int it = 0; it < 64; ++it) {
        int tl = it * 4 + (tid >> 6);
        int t = t0 + tl;
        const float* pc = &proj[(size_t)t * kProj + kI + d];
        float acc = b0 + w3 * pc[0];
        if (t >= 1) acc += w2 * pc[-(ptrdiff_t)kProj];
        if (t >= 2) acc += w1 * pc[-(ptrdiff_t)(2 * kProj)];
        if (t >= 3) acc += w0 * pc[-(ptrdiff_t)(3 * kProj)];
        T[dl][tl] = f2bf(siluf(acc));
    }
    __syncthreads();

    if (d0 < kI) {                       // X: XT[d][t], rows along t (coalesced)
        int row = tid >> 2, cg = (tid & 3) * 64;
#pragma unroll
        for (int j = 0; j < 8; ++j)
            *(ushort8v*)&XT[(size_t)(d0 + row) * kS + t0 + cg + j * 8] =
                *(const ushort8v*)&T[row][cg + j * 8];
    } else if (d0 < kI + kN) {           // B: Bt[n][t] + Bg[t][n]
        int n0 = d0 - kI;
        int row = tid >> 2, cg = (tid & 3) * 64;
#pragma unroll
        for (int j = 0; j < 8; ++j)
            *(ushort8v*)&Btg[(size_t)(n0 + row) * kS + t0 + cg + j * 8] =
                *(const ushort8v*)&T[row][cg + j * 8];
        for (int pass = 0; pass < 16; ++pass) {
            int tl = pass * 16 + (tid >> 4), nq = (tid & 15) * 4;
            ushort4 v = {T[nq][tl], T[nq + 1][tl], T[nq + 2][tl], T[nq + 3][tl]};
            *(ushort4*)&Bg[(size_t)(t0 + tl) * kN + n0 + nq] = v;
        }
    } else {                             // C: Cg[t][n]
        int n0 = d0 - (kI + kN);
        for (int pass = 0; pass < 16; ++pass) {
            int tl = pass * 16 + (tid >> 4), nq = (tid & 15) * 4;
            ushort4 v = {T[nq][tl], T[nq + 1][tl], T[nq + 2][tl], T[nq + 3][tl]};
            *(ushort4*)&Cg[(size_t)(t0 + tl) * kN + n0 + nq] = v;
        }
    }
}

// ---------- dt = softplus(proj_dt + bias); per-chunk cumsum(dt*A) ----------
__global__ __launch_bounds__(256)
void dt_cumsum_k(const float* __restrict__ proj, const float* __restrict__ dt_bias,
                 const float* __restrict__ A_log, float* __restrict__ dt,
                 float* __restrict__ acum)
{
    __shared__ float wsum[4];
    const int c = blockIdx.x >> 6, h = blockIdx.x & 63;
    const int l = threadIdx.x, t = c * kChunk + l;
    float a = -expf(A_log[h]);
    float z = proj[(size_t)t * kProj + kI + kConv + h] + dt_bias[h];
    float d = (z > 20.f) ? z : log1pf(expf(z));
    dt[t * kH + h] = d;
    float v = d * a;
    int lane = l & 63, w = l >> 6;
#pragma unroll
    for (int off = 1; off < 64; off <<= 1) {
        float u = __shfl_up(v, off);
        if (lane >= off) v += u;
    }
    if (lane == 63) wsum[w] = v;
    __syncthreads();
    float add = 0.f;
    for (int i = 0; i < w; ++i) add += wsum[i];
    acum[t * kH + h] = v + add;
}

// ---------- states (v2): bf16 MFMA. out[p][n] = sum_s Xw^T[p][s] Bt[n][s] ---
__global__ __launch_bounds__(256)
void states2_k(const unsigned short* __restrict__ XT,
               const unsigned short* __restrict__ Btg,
               const float* __restrict__ dt, const float* __restrict__ acum,
               float* __restrict__ states)
{
    __shared__ __attribute__((aligned(16))) unsigned short Aw[64 * 72];
    __shared__ __attribute__((aligned(16))) unsigned short Bs[128 * 64];
    __shared__ float Wl[256];
    const int c = blockIdx.x >> 6, h = blockIdx.x & 63;
    const int tid = threadIdx.x;
    const int wave = tid >> 6, lane = tid & 63;
    const int quad = lane >> 4, l15 = lane & 15;
    const float aend = acum[(size_t)(c * kChunk + 255) * kH + h];
    {
        int t = c * kChunk + tid;
        Wl[tid] = __expf(aend - acum[(size_t)t * kH + h]) * dt[(size_t)t * kH + h];
    }
    __syncthreads();

    floatx4 acc[4][2] = {};
    for (int lt = 0; lt < 4; ++lt) {
        const int s0 = c * kChunk + lt * 64;
#pragma unroll
        for (int i = 0; i < 2; ++i) {       // Aw[p][s] = XT * w, stride 72
            int f = tid + 256 * i;
            int p = f >> 3, sc = (f & 7) * 8;
            ushort8v xv = *(const ushort8v*)&XT[(size_t)(h * 64 + p) * kS + s0 + sc];
            ushort8v o;
#pragma unroll
            for (int j = 0; j < 8; ++j)
                o[j] = f2bf(bf2f(xv[j]) * Wl[lt * 64 + sc + j]);
            *(ushort8v*)&Aw[p * 72 + sc] = o;
        }
#pragma unroll
        for (int i = 0; i < 4; ++i) {       // Bs[n][s], phys chunk = lg ^ (n&7)
            int f = tid + 256 * i;
            int n = f >> 3, ph = f & 7, lg = ph ^ (n & 7);
            gll16(&Btg[(size_t)n * kS + s0 + lg * 8], &Bs[(size_t)f * 8]);
        }
        __syncthreads();
#pragma unroll
        for (int ks = 0; ks < 2; ++ks) {
            short8 bfr[2];
#pragma unroll
            for (int nj = 0; nj < 2; ++nj) {
                int n = (wave * 2 + nj) * 16 + l15;
                int ph = (ks * 4 + quad) ^ (n & 7);
                bfr[nj] = *(const short8*)&Bs[n * 64 + ph * 8];
            }
#pragma unroll
            for (int pi = 0; pi < 4; ++pi) {
                short8 af = *(const short8*)&Aw[(pi * 16 + l15) * 72 + ks * 32 + quad * 8];
                acc[pi][0] = __builtin_amdgcn_mfma_f32_16x16x32_bf16(af, bfr[0], acc[pi][0], 0, 0, 0);
                acc[pi][1] = __builtin_amdgcn_mfma_f32_16x16x32_bf16(af, bfr[1], acc[pi][1], 0, 0, 0);
            }
        }
        __syncthreads();
    }
    const size_t base = (size_t)(c * kH + h) * (kP * kN);
#pragma unroll
    for (int pi = 0; pi < 4; ++pi)
#pragma unroll
        for (int nj = 0; nj < 2; ++nj) {
            int n = (wave * 2 + nj) * 16 + l15;
#pragma unroll
            for (int r = 0; r < 4; ++r)
                states[base + (size_t)(pi * 16 + quad * 4 + r) * kN + n] = acc[pi][nj][r];
        }
}

// ---------- sequential inter-chunk recurrence ----------
__global__ __launch_bounds__(256)
void scan_k(const float* __restrict__ states, const float* __restrict__ acum,
            float* __restrict__ prev)
{
    const int h = blockIdx.x >> 3, seg = blockIdx.x & 7;
    const int e = (seg * 256 + threadIdx.x) * 4;
    float4 carry = make_float4(0.f, 0.f, 0.f, 0.f);
    for (int c = 0; c < kNC; ++c) {
        size_t base = (size_t)(c * kH + h) * (kP * kN);
        *(float4*)&prev[base + e] = carry;
        float dec = __expf(acum[(size_t)(c * kChunk + 255) * kH + h]);
        float4 st = *(const float4*)&states[base + e];
        carry.x = carry.x * dec + st.x; carry.y = carry.y * dec + st.y;
        carry.z = carry.z * dec + st.z; carry.w = carry.w * dec + st.w;
    }
}

// ---------- SSD Y (v4): gll16-staged bf16 tiles, XOR-swizzled ----------
__global__ __launch_bounds__(256)
void ssd_y4_k(const unsigned short* __restrict__ Cg,
              const unsigned short* __restrict__ Bg,
              const unsigned short* __restrict__ XT,
              const float* __restrict__ dt, const float* __restrict__ acum,
              const float* __restrict__ prev, const float* __restrict__ Dp,
              float* __restrict__ Y)
{
    __shared__ __attribute__((aligned(16))) unsigned short Cb[64 * 128];
    __shared__ __attribute__((aligned(16))) unsigned short Bb[64 * 128];
    __shared__ __attribute__((aligned(16))) unsigned short Xt[64 * 64];
    __shared__ __attribute__((aligned(16))) unsigned short Wb[64 * 72];
    __shared__ float At[64], Asv[64], Dtv[64];

    const int bi = blockIdx.x;
    const int ti = bi & 3, h = (bi >> 2) & 63, c = bi >> 8;
    const int tid = threadIdx.x;
    const int wave = tid >> 6, lane = tid & 63;
    const int quad = lane >> 4, l15 = lane & 15;
    const int trow0 = c * kChunk + ti * 64;
    const float Dh = Dp[h];

#pragma unroll
    for (int i = 0; i < 4; ++i) {
        int f = tid + 256 * i;
        int row = f >> 4, ph = f & 15, lg = ph ^ (row & 15);
        gll16(&Cg[(size_t)(trow0 + row) * kN + lg * 8], &Cb[(size_t)f * 8]);
    }
    const size_t pbase = (size_t)(c * kH + h) * (kP * kN);
#pragma unroll
    for (int r = 0; r < 8; ++r) {
        int f = tid + 256 * r;
        int row = f >> 5, c4 = (f & 31) * 4;          // 4 fp32 = half a 16B chunk
        float4 v = *(const float4*)&prev[pbase + (size_t)row * kN + c4];
        ushort4 u = {f2bf(v.x), f2bf(v.y), f2bf(v.z), f2bf(v.w)};
        int dst = row * 128 + ((((f & 31) >> 1) ^ (row & 15)) * 8) + (f & 1) * 4;
        *(ushort4*)&Bb[dst] = u;
    }
    if (tid < 64) At[tid] = acum[(size_t)(trow0 + tid) * kH + h];
    __syncthreads();

    floatx4 yacc[4] = {};
#pragma unroll
    for (int ks = 0; ks < 4; ++ks) {
        int cha = (ks * 4 + quad) ^ l15;
        short8 a = *(const short8*)&Cb[(wave * 16 + l15) * 128 + cha * 8];
#pragma unroll
        for (int ni = 0; ni < 4; ++ni) {
            short8 b = *(const short8*)&Bb[(ni * 16 + l15) * 128 + cha * 8];
            yacc[ni] = __builtin_amdgcn_mfma_f32_16x16x32_bf16(a, b, yacc[ni], 0, 0, 0);
        }
    }
    {
        float eAr[4];
#pragma unroll
        for (int r = 0; r < 4; ++r) eAr[r] = __expf(At[wave * 16 + quad * 4 + r]);
#pragma unroll
        for (int ni = 0; ni < 4; ++ni)
#pragma unroll
            for (int r = 0; r < 4; ++r) yacc[ni][r] *= eAr[r];
    }

    for (int si = 0; si <= ti; ++si) {
        const int srow0 = c * kChunk + si * 64;
        __syncthreads();
#pragma unroll
        for (int i = 0; i < 4; ++i) {       // B tile
            int f = tid + 256 * i;
            int row = f >> 4, ph = f & 15, lg = ph ^ (row & 15);
            gll16(&Bg[(size_t)(srow0 + row) * kN + lg * 8], &Bb[(size_t)f * 8]);
        }
#pragma unroll
        for (int i = 0; i < 2; ++i) {       // X^T tile [p][s]
            int f = tid + 256 * i;
            int p = f >> 3, ph = f & 7, lg = ph ^ (p & 7);
            gll16(&XT[(size_t)(h * 64 + p) * kS + srow0 + lg * 8], &Xt[(size_t)f * 8]);
        }
        if (tid < 64) {
            Asv[tid] = acum[(size_t)(srow0 + tid) * kH + h];
            Dtv[tid] = dt[(size_t)(srow0 + tid) * kH + h];
        }
        __syncthreads();

        floatx4 sacc[4] = {};
#pragma unroll
        for (int ks = 0; ks < 4; ++ks) {
            int cha = (ks * 4 + quad) ^ l15;
            short8 a = *(const short8*)&Cb[(wave * 16 + l15) * 128 + cha * 8];
#pragma unroll
            for (int ni = 0; ni < 4; ++ni) {
                short8 b = *(const short8*)&Bb[(ni * 16 + l15) * 128 + cha * 8];
                sacc[ni] = __builtin_amdgcn_mfma_f32_16x16x32_bf16(a, b, sacc[ni], 0, 0, 0);
            }
        }

        const bool diag = (si == ti);
#pragma unroll
        for (int ni = 0; ni < 4; ++ni) {
            int s_ = ni * 16 + l15;
            float as = Asv[s_], dts = Dtv[s_];
#pragma unroll
            for (int r = 0; r < 4; ++r) {
                int tl = wave * 16 + quad * 4 + r;
                float w = sacc[ni][r] * __expf(At[tl] - as) * dts;
                if (diag) {
                    if (s_ > tl) w = 0.f;
                    else if (s_ == tl) w += Dh;
                }
                Wb[tl * 72 + s_] = f2bf(w);
            }
        }
#pragma unroll
        for (int ks = 0; ks < 2; ++ks) {
            short8 aw = *(const short8*)&Wb[(wave * 16 + l15) * 72 + ks * 32 + quad * 8];
#pragma unroll
            for (int ni = 0; ni < 4; ++ni) {
                int ph = ((ks * 4 + quad) ^ (l15 & 7)) * 8;
                short8 xb = *(const short8*)&Xt[(ni * 16 + l15) * 64 + ph];
                yacc[ni] = __builtin_amdgcn_mfma_f32_16x16x32_bf16(aw, xb, yacc[ni], 0, 0, 0);
            }
        }
    }

#pragma unroll
    for (int ni = 0; ni < 4; ++ni)
#pragma unroll
        for (int r = 0; r < 4; ++r)
            Y[(size_t)(trow0 + wave * 16 + quad * 4 + r) * kI + h * kP + ni * 16 + l15]
                = yacc[ni][r];
}

// ---------- gated RMSNorm -> bf16 ----------
__global__ __launch_bounds__(256)
void rmsnorm_gate_k(const float* __restrict__ Y, const float* __restrict__ proj,
                    const float* __restrict__ nw, unsigned short* __restrict__ Yb)
{
    __shared__ float red[4];
    const int t = blockIdx.x, tid = threadIdx.x;
    const float* yrow = &Y[(size_t)t * kI];
    const float* grow = &proj[(size_t)t * kProj];
    float v[16];
    float ss = 0.f;
#pragma unroll
    for (int j = 0; j < 4; ++j) {
        int i = (tid + 256 * j) * 4;
        float4 y4 = *(const float4*)&yrow[i];
        float4 g4 = *(const float4*)&grow[i];
        float a = y4.x * siluf(g4.x), bq = y4.y * siluf(g4.y);
        float cq = y4.z * siluf(g4.z), d = y4.w * siluf(g4.w);
        v[j * 4 + 0] = a; v[j * 4 + 1] = bq; v[j * 4 + 2] = cq; v[j * 4 + 3] = d;
        ss += a * a + bq * bq + cq * cq + d * d;
    }
#pragma unroll
    for (int off = 32; off > 0; off >>= 1) ss += __shfl_down(ss, off);
    if ((tid & 63) == 0) red[tid >> 6] = ss;
    __syncthreads();
    float sum = red[0] + red[1] + red[2] + red[3];
    float rr = rsqrtf(sum * (1.f / kI) + kEps);
#pragma unroll
    for (int j = 0; j < 4; ++j) {
        int i = (tid + 256 * j) * 4;
        float4 w4 = *(const float4*)&nw[i];
        ushort4 o;
        o.x = f2bf(v[j * 4 + 0] * rr * w4.x);
        o.y = f2bf(v[j * 4 + 1] * rr * w4.y);
        o.z = f2bf(v[j * 4 + 2] * rr * w4.z);
        o.w = f2bf(v[j * 4 + 3] * rr * w4.w);
        *(ushort4*)&Yb[(size_t)t * kI + i] = o;
    }
}

extern "C" void kernel_launch(void* const* d_in, const int* in_sizes, int n_in,
                              void* d_out, int out_size, void* d_ws, size_t ws_size,
                              hipStream_t stream)
{
    const float* x       = (const float*)d_in[0];
    const float* W_in    = (const float*)d_in[1];
    const float* conv_w  = (const float*)d_in[2];
    const float* conv_b  = (const float*)d_in[3];
    const float* dt_bias = (const float*)d_in[4];
    const float* A_log   = (const float*)d_in[5];
    const float* Dp      = (const float*)d_in[6];
    const float* norm_w  = (const float*)d_in[7];
    const float* W_out   = (const float*)d_in[8];
    float* out = (float*)d_out;

    float* ws   = (float*)d_ws;
    float* proj = ws;                                       // 2048*8512 f
    unsigned short* XT  = (unsigned short*)(proj + (size_t)kS * kProj);  // 4096*2048
    unsigned short* Bg  = XT + (size_t)kI * kS;             // 2048*128
    unsigned short* Btg = Bg + (size_t)kS * kN;             // 128*2048
    unsigned short* Cg  = Btg + (size_t)kN * kS;            // 2048*128
    float* dtb  = (float*)(Cg + (size_t)kS * kN);           // 2048*64
    float* acum = dtb + (size_t)kS * kH;                    // 2048*64
    float* prev = acum + (size_t)kS * kH;                   // 4,194,304 f
    float* Y    = prev + (size_t)kNC * kH * kP * kN;        // 8,388,608 f
    float* states = Y;
    unsigned short* xb  = XT;                               // early alias
    unsigned short* Wb  = (unsigned short*)prev;            // early (8.7M f < 12.6M)
    unsigned short* Yb  = (unsigned short*)prev;            // late
    unsigned short* Wob = XT;                               // late

    dim3 blk(256);
    const int NtO = kHID / 128;            // 16
    const int Mt8 = kS >> 8;               // 8
    const int Nt8 = (kProj + 255) >> 8;    // 34
    cast_bf16_k<<<(kS * kHID) / 2048, blk, 0, stream>>>(x, xb);
    cast_bf16_k<<<(kProj * kHID) / 2048, blk, 0, stream>>>(W_in, Wb);
    gemm_bt_8ph<<<Mt8 * Nt8, dim3(512), 0, stream>>>(xb, Wb, proj, kS, kProj, kHID);
    conv_silu2_k<<<68 * 8, blk, 0, stream>>>(proj, conv_w, conv_b, XT, Bg, Btg, Cg);
    dt_cumsum_k<<<kNC * kH, blk, 0, stream>>>(proj, dt_bias, A_log, dtb, acum);
    states2_k<<<kNC * kH, blk, 0, stream>>>(XT, Btg, dtb, acum, states);
    scan_k<<<kH * 8, blk, 0, stream>>>(states, acum, prev);
    ssd_y4_k<<<kNC * kH * 4, blk, 0, stream>>>(Cg, Bg, XT, dtb, acum, prev, Dp, Y);
    rmsnorm_gate_k<<<kS, blk, 0, stream>>>(Y, proj, norm_w, Yb);
    cast_bf16_k<<<(kHID * kI) / 2048, blk, 0, stream>>>(W_out, Wob);
    gemm_bt_bf16<<<NtO * 16, blk, 0, stream>>>(Yb, Wob, out, kS, kHID, kI);
}

// Round 2
// 504.447 us; speedup vs baseline: 1.1660x; 1.1660x over previous
//
#include <hip/hip_runtime.h>
#include <math.h>

// Bamba-9B mixer, b=1 s=2048. Round 9: fix the 8-phase proj GEMM.
//  - Root cause of round-8 regression: (a) single LDS array => compiler's
//    LDS-DMA hazard pass inserted near-drain vmcnt waits before every phase's
//    ds_reads (must-alias), collapsing the counted-vmcnt pipeline; (b) 272
//    blocks at 1 block/CU = 2 serial rounds (1.88x makespan).
//  - Fix: 4 separate __shared__ arrays (A0s/B0s/A1s/B1s) so auto-waits become
//    counted no-ops against the hand-placed vmcnt(6); proj tiled as 256 blocks
//    (N=8192) + 320-col strip on the proven 128^2 kernel; ldc param for both.
//  - sched_barrier(0) after each lgkmcnt(0) (rule #18), lgkmcnt(8) hint in the
//    16-read phase.
// Everything downstream of proj unchanged.
static constexpr int kS     = 2048;
static constexpr int kHID   = 2048;
static constexpr int kI     = 4096;
static constexpr int kH     = 64;
static constexpr int kP     = 64;
static constexpr int kN     = 128;
static constexpr int kConv  = 4352;   // I + 2*G*N
static constexpr int kProj  = 8512;   // I + CONV + H
static constexpr int kChunk = 256;
static constexpr int kNC    = 8;
static constexpr float kEps = 1e-5f;

typedef __attribute__((ext_vector_type(8))) short short8;            // bf16 frag
typedef __attribute__((ext_vector_type(8))) unsigned short ushort8v;
typedef __attribute__((ext_vector_type(4))) float floatx4;

__device__ __forceinline__ float siluf(float x) {
    return x / (1.f + __expf(-x));
}
__device__ __forceinline__ unsigned short f2bf(float f) {   // RNE, finite
    unsigned int u = __float_as_uint(f);
    return (unsigned short)((u + 0x7FFFu + ((u >> 16) & 1u)) >> 16);
}
__device__ __forceinline__ float bf2f(unsigned short u) {
    return __uint_as_float((unsigned int)u << 16);
}
__device__ __forceinline__ void gll16(const void* g, void* l) {
    __builtin_amdgcn_global_load_lds(
        (const __attribute__((address_space(1))) void*)g,
        (__attribute__((address_space(3))) void*)l, 16, 0, 0);
}

// ---------- fp32 -> bf16 cast, 8 elems/thread ----------
__global__ __launch_bounds__(256)
void cast_bf16_k(const float* __restrict__ in, unsigned short* __restrict__ out)
{
    size_t i = ((size_t)blockIdx.x * 256 + threadIdx.x) * 8;
    float4 a = *(const float4*)&in[i];
    float4 b = *(const float4*)&in[i + 4];
    ushort4 u0 = {f2bf(a.x), f2bf(a.y), f2bf(a.z), f2bf(a.w)};
    ushort4 u1 = {f2bf(b.x), f2bf(b.y), f2bf(b.z), f2bf(b.w)};
    *(ushort4*)&out[i] = u0;
    *(ushort4*)&out[i + 4] = u1;
}

// ---------- 256x256-tile 8-phase bf16 NT GEMM (proj GEMM main) ----------
// Requires M % 256 == 0, N % 256 == 0, K % 128 == 0.
// Per K-tile (4 phases): ph1 reads all 8 B-frags + 8 A-k0 frags, stages
// (t+1)B1; ph2 reads 8 A-k1 frags, stages (t+2)B0; ph3/ph4 stage (t+2)A0/A1.
// vmcnt(6) once per K-tile (3 half-tiles stay in flight). Four distinct
// __shared__ arrays so the compiler's LDS-DMA hazard waits are counted
// per-array no-ops instead of queue drains.
#define MF16(acc_, a_, b_) \
    acc_ = __builtin_amdgcn_mfma_f32_16x16x32_bf16(a_, b_, acc_, 0, 0, 0)

#define PH_SYNC()                                              \
    __builtin_amdgcn_s_barrier();                              \
    asm volatile("s_waitcnt lgkmcnt(0)" ::: "memory");         \
    __builtin_amdgcn_sched_barrier(0);                         \
    __builtin_amdgcn_s_setprio(1);

#define PH_END()                                               \
    __builtin_amdgcn_s_setprio(0);                             \
    __builtin_amdgcn_s_barrier();

#define GROUP8(LA, LB, S1, S2, S3, S4, VMTAIL)                                 \
    {                                                                          \
        short8 a0[8], a1[8], bq[4][2];                                         \
        _Pragma("unroll")                                                      \
        for (int n = 0; n < 4; ++n) {                                          \
            bq[n][0] = *(const short8*)&(LB)[boff + (n << 10) + ph0];          \
            bq[n][1] = *(const short8*)&(LB)[boff + (n << 10) + ph1];          \
        }                                                                      \
        _Pragma("unroll")                                                      \
        for (int m = 0; m < 8; ++m)                                            \
            a0[m] = *(const short8*)&(LA)[aoff + (m << 10) + ph0];             \
        S1;                                                                    \
        asm volatile("s_waitcnt lgkmcnt(8)" ::: "memory");                     \
        PH_SYNC();                                                             \
        _Pragma("unroll")                                                      \
        for (int m = 0; m < 8; ++m) {                                          \
            MF16(acc[m][0], a0[m], bq[0][0]);                                  \
            MF16(acc[m][1], a0[m], bq[1][0]);                                  \
        }                                                                      \
        PH_END();                                                              \
        _Pragma("unroll")                                                      \
        for (int m = 0; m < 8; ++m)                                            \
            a1[m] = *(const short8*)&(LA)[aoff + (m << 10) + ph1];             \
        S2;                                                                    \
        PH_SYNC();                                                             \
        _Pragma("unroll")                                                      \
        for (int m = 0; m < 8; ++m) {                                          \
            MF16(acc[m][2], a0[m], bq[2][0]);                                  \
            MF16(acc[m][3], a0[m], bq[3][0]);                                  \
        }                                                                      \
        PH_END();                                                              \
        S3;                                                                    \
        PH_SYNC();                                                             \
        _Pragma("unroll")                                                      \
        for (int m = 0; m < 8; ++m) {                                          \
            MF16(acc[m][0], a1[m], bq[0][1]);                                  \
            MF16(acc[m][1], a1[m], bq[1][1]);                                  \
        }                                                                      \
        PH_END();                                                              \
        S4;                                                                    \
        PH_SYNC();                                                             \
        _Pragma("unroll")                                                      \
        for (int m = 0; m < 8; ++m) {                                          \
            MF16(acc[m][2], a1[m], bq[2][1]);                                  \
            MF16(acc[m][3], a1[m], bq[3][1]);                                  \
        }                                                                      \
        __builtin_amdgcn_s_setprio(0);                                         \
        VMTAIL;                                                                \
        __builtin_amdgcn_s_barrier();                                          \
    }

__global__ __launch_bounds__(512)
void gemm_bt_8ph(const unsigned short* __restrict__ A,
                 const unsigned short* __restrict__ B,
                 float* __restrict__ C, int M, int N, int K, int ldc)
{
    __shared__ __attribute__((aligned(16))) unsigned short A0s[16384];
    __shared__ __attribute__((aligned(16))) unsigned short B0s[16384];
    __shared__ __attribute__((aligned(16))) unsigned short A1s[16384];
    __shared__ __attribute__((aligned(16))) unsigned short B1s[16384];
    const int tid = threadIdx.x;
    const int lane = tid & 63, wave = tid >> 6;
    const int quad = lane >> 4, l15 = lane & 15;
    const int wm = wave >> 2, wn = wave & 3;

    // bijective XCD swizzle (m204), then nt-major / mt-fast tile order.
    const int Mt = M >> 8, Nt = N >> 8;
    const int nwg = Mt * Nt;
    const int q = nwg >> 3, r = nwg & 7;
    const int xcd = blockIdx.x & 7, idx = blockIdx.x >> 3;
    const int wgid = (xcd < r ? xcd * (q + 1) : r * (q + 1) + (xcd - r) * q) + idx;
    const int mt = wgid % Mt, nt = wgid / Mt;
    const int m0 = mt << 8, n0 = nt << 8;

    auto stA = [&](unsigned short* arr, int t, int hh) {
        const int k0 = t << 6;
#pragma unroll
        for (int i = 0; i < 2; ++i) {
            const int f = tid + (i << 9);
            const int rr = f >> 3, lc = (f & 7) ^ (rr & 7);
            gll16(&A[(size_t)(m0 + (hh << 7) + rr) * K + k0 + (lc << 3)],
                  &arr[(hh << 13) + ((size_t)f << 3)]);
        }
    };
    auto stB = [&](unsigned short* arr, int t, int hh) {
        const int k0 = t << 6;
#pragma unroll
        for (int i = 0; i < 2; ++i) {
            const int f = tid + (i << 9);
            const int rr = f >> 3, lc = (f & 7) ^ (rr & 7);
            gll16(&B[(size_t)(n0 + (hh << 7) + rr) * K + k0 + (lc << 3)],
                  &arr[(hh << 13) + ((size_t)f << 3)]);
        }
    };

    floatx4 acc[8][4] = {};

    const int aoff = ((wm << 7) + l15) << 6;             // A row base (shorts)
    const int boff = ((wn << 6) + l15) << 6;             // B row base
    const int ph0 = (quad ^ (l15 & 7)) << 3;             // k=0 phys chunk
    const int ph1 = ((quad + 4) ^ (l15 & 7)) << 3;       // k=1 phys chunk

    // prologue: tile0 all 4 halves, tile1 {B0,A0,A1}; leave those 3 in flight.
    stA(A0s, 0, 0); stA(A0s, 0, 1); stB(B0s, 0, 0); stB(B0s, 0, 1);
    stB(B1s, 1, 0); stA(A1s, 1, 0); stA(A1s, 1, 1);
    asm volatile("s_waitcnt vmcnt(6)" ::: "memory");
    __builtin_amdgcn_s_barrier();

    const int NITER = K >> 7;   // tile pairs
    for (int it = 0; it < NITER; ++it) {
        const int t = it << 1;
        const bool nl = (it + 1 < NITER);
        // group A: tile t (buffer 0)
        GROUP8(A0s, B0s,
               stB(B1s, t + 1, 1),
               if (nl) stB(B0s, t + 2, 0),
               if (nl) stA(A0s, t + 2, 0),
               if (nl) stA(A0s, t + 2, 1),
               if (nl) asm volatile("s_waitcnt vmcnt(6)" ::: "memory");
               else    asm volatile("s_waitcnt vmcnt(0)" ::: "memory"))
        // group B: tile t+1 (buffer 1)
        GROUP8(A1s, B1s,
               if (nl) stB(B0s, t + 2, 1),
               if (nl) stB(B1s, t + 3, 0),
               if (nl) stA(A1s, t + 3, 0),
               if (nl) stA(A1s, t + 3, 1),
               if (nl) asm volatile("s_waitcnt vmcnt(6)" ::: "memory"))
    }

#pragma unroll
    for (int m = 0; m < 8; ++m) {
        const int row = m0 + (wm << 7) + m * 16 + (quad << 2);
#pragma unroll
        for (int n = 0; n < 4; ++n) {
            const int col = n0 + (wn << 6) + n * 16 + l15;
#pragma unroll
            for (int rr = 0; rr < 4; ++rr)
                C[(size_t)(row + rr) * ldc + col] = acc[m][n][rr];
        }
    }
}

// ---------- bf16 MFMA NT GEMM (128^2 m97 structure; strip + out GEMM) ------
__global__ __launch_bounds__(256)
void gemm_bt_bf16(const unsigned short* __restrict__ A,
                  const unsigned short* __restrict__ B,
                  float* __restrict__ C, int M, int N, int K, int ldc)
{
    __shared__ unsigned short As[128 * 64];
    __shared__ unsigned short Bs[128 * 64];
    const int tid = threadIdx.x;
    const int lane = tid & 63, quad = lane >> 4, l15 = lane & 15;
    const int wave = tid >> 6;

    const int Nt = (N + 127) >> 7;
    const int mainN = Nt & ~7;
    int bi = blockIdx.x, mt, nt;
    if (bi < mainN * 16) {
        nt = ((bi >> 7) << 3) | (bi & 7);
        mt = (bi >> 3) & 15;
    } else {
        int r = bi - mainN * 16, rem = Nt - mainN;
        nt = mainN + r % rem; mt = r / rem;
    }
    const int m0 = mt * 128, n0 = nt * 128;
    const int wm = (wave & 1) * 64, wn = (wave >> 1) * 64;

    floatx4 acc[4][4] = {};

    int rowS[4], lcS[4];
#pragma unroll
    for (int i = 0; i < 4; ++i) {
        int f = tid + 256 * i;
        rowS[i] = f >> 3;
        lcS[i] = ((f & 7) ^ (rowS[i] & 7)) * 8;
    }

    for (int k0 = 0; k0 < K; k0 += 64) {
#pragma unroll
        for (int i = 0; i < 4; ++i) {
            int ra = m0 + rowS[i];
            gll16(&A[(size_t)ra * K + k0 + lcS[i]], &As[(size_t)(tid + 256 * i) * 8]);
        }
#pragma unroll
        for (int i = 0; i < 4; ++i) {
            int rb = n0 + rowS[i]; if (rb > N - 1) rb = N - 1;
            gll16(&B[(size_t)rb * K + k0 + lcS[i]], &Bs[(size_t)(tid + 256 * i) * 8]);
        }
        __syncthreads();

        short8 af[4][2], bf[4][2];
#pragma unroll
        for (int ks = 0; ks < 2; ++ks) {
            const int ph = ((ks * 4 + quad) ^ (l15 & 7)) * 8;
#pragma unroll
            for (int mi = 0; mi < 4; ++mi)
                af[mi][ks] = *(const short8*)&As[(size_t)(wm + mi * 16 + l15) * 64 + ph];
#pragma unroll
            for (int ni = 0; ni < 4; ++ni)
                bf[ni][ks] = *(const short8*)&Bs[(size_t)(wn + ni * 16 + l15) * 64 + ph];
        }
#pragma unroll
        for (int ks = 0; ks < 2; ++ks)
#pragma unroll
            for (int mi = 0; mi < 4; ++mi)
#pragma unroll
                for (int ni = 0; ni < 4; ++ni)
                    acc[mi][ni] = __builtin_amdgcn_mfma_f32_16x16x32_bf16(
                        af[mi][ks], bf[ni][ks], acc[mi][ni], 0, 0, 0);
        __syncthreads();
    }

#pragma unroll
    for (int mi = 0; mi < 4; ++mi)
#pragma unroll
        for (int ni = 0; ni < 4; ++ni) {
            int col = n0 + wn + ni * 16 + l15;
            if (col < N) {
#pragma unroll
                for (int r = 0; r < 4; ++r) {
                    int row = m0 + wm + mi * 16 + quad * 4 + r;
                    C[(size_t)row * ldc + col] = acc[mi][ni][r];
                }
            }
        }
}

// ---------- conv+SiLU -> bf16 consumer layouts ----------
__global__ __launch_bounds__(256)
void conv_silu2_k(const float* __restrict__ proj, const float* __restrict__ cw,
                  const float* __restrict__ cb,
                  unsigned short* __restrict__ XT, unsigned short* __restrict__ Bg,
                  unsigned short* __restrict__ Btg, unsigned short* __restrict__ Cg)
{
    __shared__ __attribute__((aligned(16))) unsigned short T[64][264];
    const int bd = blockIdx.x % 68, bt = blockIdx.x / 68;
    const int d0 = bd * 64, t0 = bt * 256;
    const int tid = threadIdx.x;
    const int dl = tid & 63;
    const int d = d0 + dl;
    const float b0 = cb[d];
    const float w0 = cw[d * 4 + 0], w1 = cw[d * 4 + 1];
    const float w2 = cw[d * 4 + 2], w3 = cw[d * 4 + 3];
    for (int it = 0; it < 64; ++it) {
        int tl = it * 4 + (tid >> 6);
        int t = t0 + tl;
        const float* pc = &proj[(size_t)t * kProj + kI + d];
        float acc = b0 + w3 * pc[0];
        if (t >= 1) acc += w2 * pc[-(ptrdiff_t)kProj];
        if (t >= 2) acc += w1 * pc[-(ptrdiff_t)(2 * kProj)];
        if (t >= 3) acc += w0 * pc[-(ptrdiff_t)(3 * kProj)];
        T[dl][tl] = f2bf(siluf(acc));
    }
    __syncthreads();

    if (d0 < kI) {                       // X: XT[d][t], rows along t (coalesced)
        int row = tid >> 2, cg = (tid & 3) * 64;
#pragma unroll
        for (int j = 0; j < 8; ++j)
            *(ushort8v*)&XT[(size_t)(d0 + row) * kS + t0 + cg + j * 8] =
                *(const ushort8v*)&T[row][cg + j * 8];
    } else if (d0 < kI + kN) {           // B: Bt[n][t] + Bg[t][n]
        int n0 = d0 - kI;
        int row = tid >> 2, cg = (tid & 3) * 64;
#pragma unroll
        for (int j = 0; j < 8; ++j)
            *(ushort8v*)&Btg[(size_t)(n0 + row) * kS + t0 + cg + j * 8] =
                *(const ushort8v*)&T[row][cg + j * 8];
        for (int pass = 0; pass < 16; ++pass) {
            int tl = pass * 16 + (tid >> 4), nq = (tid & 15) * 4;
            ushort4 v = {T[nq][tl], T[nq + 1][tl], T[nq + 2][tl], T[nq + 3][tl]};
            *(ushort4*)&Bg[(size_t)(t0 + tl) * kN + n0 + nq] = v;
        }
    } else {                             // C: Cg[t][n]
        int n0 = d0 - (kI + kN);
        for (int pass = 0; pass < 16; ++pass) {
            int tl = pass * 16 + (tid >> 4), nq = (tid & 15) * 4;
            ushort4 v = {T[nq][tl], T[nq + 1][tl], T[nq + 2][tl], T[nq + 3][tl]};
            *(ushort4*)&Cg[(size_t)(t0 + tl) * kN + n0 + nq] = v;
        }
    }
}

// ---------- dt = softplus(proj_dt + bias); per-chunk cumsum(dt*A) ----------
__global__ __launch_bounds__(256)
void dt_cumsum_k(const float* __restrict__ proj, const float* __restrict__ dt_bias,
                 const float* __restrict__ A_log, float* __restrict__ dt,
                 float* __restrict__ acum)
{
    __shared__ float wsum[4];
    const int c = blockIdx.x >> 6, h = blockIdx.x & 63;
    const int l = threadIdx.x, t = c * kChunk + l;
    float a = -expf(A_log[h]);
    float z = proj[(size_t)t * kProj + kI + kConv + h] + dt_bias[h];
    float d = (z > 20.f) ? z : log1pf(expf(z));
    dt[t * kH + h] = d;
    float v = d * a;
    int lane = l & 63, w = l >> 6;
#pragma unroll
    for (int off = 1; off < 64; off <<= 1) {
        float u = __shfl_up(v, off);
        if (lane >= off) v += u;
    }
    if (lane == 63) wsum[w] = v;
    __syncthreads();
    float add = 0.f;
    for (int i = 0; i < w; ++i) add += wsum[i];
    acum[t * kH + h] = v + add;
}

// ---------- states (v2): bf16 MFMA. out[p][n] = sum_s Xw^T[p][s] Bt[n][s] ---
__global__ __launch_bounds__(256)
void states2_k(const unsigned short* __restrict__ XT,
               const unsigned short* __restrict__ Btg,
               const float* __restrict__ dt, const float* __restrict__ acum,
               float* __restrict__ states)
{
    __shared__ __attribute__((aligned(16))) unsigned short Aw[64 * 72];
    __shared__ __attribute__((aligned(16))) unsigned short Bs[128 * 64];
    __shared__ float Wl[256];
    const int c = blockIdx.x >> 6, h = blockIdx.x & 63;
    const int tid = threadIdx.x;
    const int wave = tid >> 6, lane = tid & 63;
    const int quad = lane >> 4, l15 = lane & 15;
    const float aend = acum[(size_t)(c * kChunk + 255) * kH + h];
    {
        int t = c * kChunk + tid;
        Wl[tid] = __expf(aend - acum[(size_t)t * kH + h]) * dt[(size_t)t * kH + h];
    }
    __syncthreads();

    floatx4 acc[4][2] = {};
    for (int lt = 0; lt < 4; ++lt) {
        const int s0 = c * kChunk + lt * 64;
#pragma unroll
        for (int i = 0; i < 2; ++i) {       // Aw[p][s] = XT * w, stride 72
            int f = tid + 256 * i;
            int p = f >> 3, sc = (f & 7) * 8;
            ushort8v xv = *(const ushort8v*)&XT[(size_t)(h * 64 + p) * kS + s0 + sc];
            ushort8v o;
#pragma unroll
            for (int j = 0; j < 8; ++j)
                o[j] = f2bf(bf2f(xv[j]) * Wl[lt * 64 + sc + j]);
            *(ushort8v*)&Aw[p * 72 + sc] = o;
        }
#pragma unroll
        for (int i = 0; i < 4; ++i) {       // Bs[n][s], phys chunk = lg ^ (n&7)
            int f = tid + 256 * i;
            int n = f >> 3, ph = f & 7, lg = ph ^ (n & 7);
            gll16(&Btg[(size_t)n * kS + s0 + lg * 8], &Bs[(size_t)f * 8]);
        }
        __syncthreads();
#pragma unroll
        for (int ks = 0; ks < 2; ++ks) {
            short8 bfr[2];
#pragma unroll
            for (int nj = 0; nj < 2; ++nj) {
                int n = (wave * 2 + nj) * 16 + l15;
                int ph = (ks * 4 + quad) ^ (n & 7);
                bfr[nj] = *(const short8*)&Bs[n * 64 + ph * 8];
            }
#pragma unroll
            for (int pi = 0; pi < 4; ++pi) {
                short8 af = *(const short8*)&Aw[(pi * 16 + l15) * 72 + ks * 32 + quad * 8];
                acc[pi][0] = __builtin_amdgcn_mfma_f32_16x16x32_bf16(af, bfr[0], acc[pi][0], 0, 0, 0);
                acc[pi][1] = __builtin_amdgcn_mfma_f32_16x16x32_bf16(af, bfr[1], acc[pi][1], 0, 0, 0);
            }
        }
        __syncthreads();
    }
    const size_t base = (size_t)(c * kH + h) * (kP * kN);
#pragma unroll
    for (int pi = 0; pi < 4; ++pi)
#pragma unroll
        for (int nj = 0; nj < 2; ++nj) {
            int n = (wave * 2 + nj) * 16 + l15;
#pragma unroll
            for (int r = 0; r < 4; ++r)
                states[base + (size_t)(pi * 16 + quad * 4 + r) * kN + n] = acc[pi][nj][r];
        }
}

// ---------- sequential inter-chunk recurrence ----------
__global__ __launch_bounds__(256)
void scan_k(const float* __restrict__ states, const float* __restrict__ acum,
            float* __restrict__ prev)
{
    const int h = blockIdx.x >> 3, seg = blockIdx.x & 7;
    const int e = (seg * 256 + threadIdx.x) * 4;
    float4 carry = make_float4(0.f, 0.f, 0.f, 0.f);
    for (int c = 0; c < kNC; ++c) {
        size_t base = (size_t)(c * kH + h) * (kP * kN);
        *(float4*)&prev[base + e] = carry;
        float dec = __expf(acum[(size_t)(c * kChunk + 255) * kH + h]);
        float4 st = *(const float4*)&states[base + e];
        carry.x = carry.x * dec + st.x; carry.y = carry.y * dec + st.y;
        carry.z = carry.z * dec + st.z; carry.w = carry.w * dec + st.w;
    }
}

// ---------- SSD Y (v4): gll16-staged bf16 tiles, XOR-swizzled ----------
__global__ __launch_bounds__(256)
void ssd_y4_k(const unsigned short* __restrict__ Cg,
              const unsigned short* __restrict__ Bg,
              const unsigned short* __restrict__ XT,
              const float* __restrict__ dt, const float* __restrict__ acum,
              const float* __restrict__ prev, const float* __restrict__ Dp,
              float* __restrict__ Y)
{
    __shared__ __attribute__((aligned(16))) unsigned short Cb[64 * 128];
    __shared__ __attribute__((aligned(16))) unsigned short Bb[64 * 128];
    __shared__ __attribute__((aligned(16))) unsigned short Xt[64 * 64];
    __shared__ __attribute__((aligned(16))) unsigned short Wb[64 * 72];
    __shared__ float At[64], Asv[64], Dtv[64];

    const int bi = blockIdx.x;
    const int ti = bi & 3, h = (bi >> 2) & 63, c = bi >> 8;
    const int tid = threadIdx.x;
    const int wave = tid >> 6, lane = tid & 63;
    const int quad = lane >> 4, l15 = lane & 15;
    const int trow0 = c * kChunk + ti * 64;
    const float Dh = Dp[h];

#pragma unroll
    for (int i = 0; i < 4; ++i) {
        int f = tid + 256 * i;
        int row = f >> 4, ph = f & 15, lg = ph ^ (row & 15);
        gll16(&Cg[(size_t)(trow0 + row) * kN + lg * 8], &Cb[(size_t)f * 8]);
    }
    const size_t pbase = (size_t)(c * kH + h) * (kP * kN);
#pragma unroll
    for (int r = 0; r < 8; ++r) {
        int f = tid + 256 * r;
        int row = f >> 5, c4 = (f & 31) * 4;          // 4 fp32 = half a 16B chunk
        float4 v = *(const float4*)&prev[pbase + (size_t)row * kN + c4];
        ushort4 u = {f2bf(v.x), f2bf(v.y), f2bf(v.z), f2bf(v.w)};
        int dst = row * 128 + ((((f & 31) >> 1) ^ (row & 15)) * 8) + (f & 1) * 4;
        *(ushort4*)&Bb[dst] = u;
    }
    if (tid < 64) At[tid] = acum[(size_t)(trow0 + tid) * kH + h];
    __syncthreads();

    floatx4 yacc[4] = {};
#pragma unroll
    for (int ks = 0; ks < 4; ++ks) {
        int cha = (ks * 4 + quad) ^ l15;
        short8 a = *(const short8*)&Cb[(wave * 16 + l15) * 128 + cha * 8];
#pragma unroll
        for (int ni = 0; ni < 4; ++ni) {
            short8 b = *(const short8*)&Bb[(ni * 16 + l15) * 128 + cha * 8];
            yacc[ni] = __builtin_amdgcn_mfma_f32_16x16x32_bf16(a, b, yacc[ni], 0, 0, 0);
        }
    }
    {
        float eAr[4];
#pragma unroll
        for (int r = 0; r < 4; ++r) eAr[r] = __expf(At[wave * 16 + quad * 4 + r]);
#pragma unroll
        for (int ni = 0; ni < 4; ++ni)
#pragma unroll
            for (int r = 0; r < 4; ++r) yacc[ni][r] *= eAr[r];
    }

    for (int si = 0; si <= ti; ++si) {
        const int srow0 = c * kChunk + si * 64;
        __syncthreads();
#pragma unroll
        for (int i = 0; i < 4; ++i) {       // B tile
            int f = tid + 256 * i;
            int row = f >> 4, ph = f & 15, lg = ph ^ (row & 15);
            gll16(&Bg[(size_t)(srow0 + row) * kN + lg * 8], &Bb[(size_t)f * 8]);
        }
#pragma unroll
        for (int i = 0; i < 2; ++i) {       // X^T tile [p][s]
            int f = tid + 256 * i;
            int p = f >> 3, ph = f & 7, lg = ph ^ (p & 7);
            gll16(&XT[(size_t)(h * 64 + p) * kS + srow0 + lg * 8], &Xt[(size_t)f * 8]);
        }
        if (tid < 64) {
            Asv[tid] = acum[(size_t)(srow0 + tid) * kH + h];
            Dtv[tid] = dt[(size_t)(srow0 + tid) * kH + h];
        }
        __syncthreads();

        floatx4 sacc[4] = {};
#pragma unroll
        for (int ks = 0; ks < 4; ++ks) {
            int cha = (ks * 4 + quad) ^ l15;
            short8 a = *(const short8*)&Cb[(wave * 16 + l15) * 128 + cha * 8];
#pragma unroll
            for (int ni = 0; ni < 4; ++ni) {
                short8 b = *(const short8*)&Bb[(ni * 16 + l15) * 128 + cha * 8];
                sacc[ni] = __builtin_amdgcn_mfma_f32_16x16x32_bf16(a, b, sacc[ni], 0, 0, 0);
            }
        }

        const bool diag = (si == ti);
#pragma unroll
        for (int ni = 0; ni < 4; ++ni) {
            int s_ = ni * 16 + l15;
            float as = Asv[s_], dts = Dtv[s_];
#pragma unroll
            for (int r = 0; r < 4; ++r) {
                int tl = wave * 16 + quad * 4 + r;
                float w = sacc[ni][r] * __expf(At[tl] - as) * dts;
                if (diag) {
                    if (s_ > tl) w = 0.f;
                    else if (s_ == tl) w += Dh;
                }
                Wb[tl * 72 + s_] = f2bf(w);
            }
        }
#pragma unroll
        for (int ks = 0; ks < 2; ++ks) {
            short8 aw = *(const short8*)&Wb[(wave * 16 + l15) * 72 + ks * 32 + quad * 8];
#pragma unroll
            for (int ni = 0; ni < 4; ++ni) {
                int ph = ((ks * 4 + quad) ^ (l15 & 7)) * 8;
                short8 xb = *(const short8*)&Xt[(ni * 16 + l15) * 64 + ph];
                yacc[ni] = __builtin_amdgcn_mfma_f32_16x16x32_bf16(aw, xb, yacc[ni], 0, 0, 0);
            }
        }
    }

#pragma unroll
    for (int ni = 0; ni < 4; ++ni)
#pragma unroll
        for (int r = 0; r < 4; ++r)
            Y[(size_t)(trow0 + wave * 16 + quad * 4 + r) * kI + h * kP + ni * 16 + l15]
                = yacc[ni][r];
}

// ---------- gated RMSNorm -> bf16 ----------
__global__ __launch_bounds__(256)
void rmsnorm_gate_k(const float* __restrict__ Y, const float* __restrict__ proj,
                    const float* __restrict__ nw, unsigned short* __restrict__ Yb)
{
    __shared__ float red[4];
    const int t = blockIdx.x, tid = threadIdx.x;
    const float* yrow = &Y[(size_t)t * kI];
    const float* grow = &proj[(size_t)t * kProj];
    float v[16];
    float ss = 0.f;
#pragma unroll
    for (int j = 0; j < 4; ++j) {
        int i = (tid + 256 * j) * 4;
        float4 y4 = *(const float4*)&yrow[i];
        float4 g4 = *(const float4*)&grow[i];
        float a = y4.x * siluf(g4.x), bq = y4.y * siluf(g4.y);
        float cq = y4.z * siluf(g4.z), d = y4.w * siluf(g4.w);
        v[j * 4 + 0] = a; v[j * 4 + 1] = bq; v[j * 4 + 2] = cq; v[j * 4 + 3] = d;
        ss += a * a + bq * bq + cq * cq + d * d;
    }
#pragma unroll
    for (int off = 32; off > 0; off >>= 1) ss += __shfl_down(ss, off);
    if ((tid & 63) == 0) red[tid >> 6] = ss;
    __syncthreads();
    float sum = red[0] + red[1] + red[2] + red[3];
    float rr = rsqrtf(sum * (1.f / kI) + kEps);
#pragma unroll
    for (int j = 0; j < 4; ++j) {
        int i = (tid + 256 * j) * 4;
        float4 w4 = *(const float4*)&nw[i];
        ushort4 o;
        o.x = f2bf(v[j * 4 + 0] * rr * w4.x);
        o.y = f2bf(v[j * 4 + 1] * rr * w4.y);
        o.z = f2bf(v[j * 4 + 2] * rr * w4.z);
        o.w = f2bf(v[j * 4 + 3] * rr * w4.w);
        *(ushort4*)&Yb[(size_t)t * kI + i] = o;
    }
}

extern "C" void kernel_launch(void* const* d_in, const int* in_sizes, int n_in,
                              void* d_out, int out_size, void* d_ws, size_t ws_size,
                              hipStream_t stream)
{
    const float* x       = (const float*)d_in[0];
    const float* W_in    = (const float*)d_in[1];
    const float* conv_w  = (const float*)d_in[2];
    const float* conv_b  = (const float*)d_in[3];
    const float* dt_bias = (const float*)d_in[4];
    const float* A_log   = (const float*)d_in[5];
    const float* Dp      = (const float*)d_in[6];
    const float* norm_w  = (const float*)d_in[7];
    const float* W_out   = (const float*)d_in[8];
    float* out = (float*)d_out;

    float* ws   = (float*)d_ws;
    float* proj = ws;                                       // 2048*8512 f
    unsigned short* XT  = (unsigned short*)(proj + (size_t)kS * kProj);  // 4096*2048
    unsigned short* Bg  = XT + (size_t)kI * kS;             // 2048*128
    unsigned short* Btg = Bg + (size_t)kS * kN;             // 128*2048
    unsigned short* Cg  = Btg + (size_t)kN * kS;            // 2048*128
    float* dtb  = (float*)(Cg + (size_t)kS * kN);           // 2048*64
    float* acum = dtb + (size_t)kS * kH;                    // 2048*64
    float* prev = acum + (size_t)kS * kH;                   // 4,194,304 f
    float* Y    = prev + (size_t)kNC * kH * kP * kN;        // 8,388,608 f
    float* states = Y;
    unsigned short* xb  = XT;                               // early alias
    unsigned short* Wb  = (unsigned short*)prev;            // early (8.7M f < 12.6M)
    unsigned short* Yb  = (unsigned short*)prev;            // late
    unsigned short* Wob = XT;                               // late

    dim3 blk(256);
    const int NtO = kHID / 128;            // 16
    const int kNmain = 8192;               // 32 x 256-col tiles -> 256 blocks
    const int kNstrip = kProj - kNmain;    // 320 -> 3 x 128-col tiles, 48 blocks
    cast_bf16_k<<<(kS * kHID) / 2048, blk, 0, stream>>>(x, xb);
    cast_bf16_k<<<(kProj * kHID) / 2048, blk, 0, stream>>>(W_in, Wb);
    gemm_bt_8ph<<<(kS >> 8) * (kNmain >> 8), dim3(512), 0, stream>>>(
        xb, Wb, proj, kS, kNmain, kHID, kProj);
    gemm_bt_bf16<<<(kS / 128) * 3, blk, 0, stream>>>(
        xb, Wb + (size_t)kNmain * kHID, proj + kNmain, kS, kNstrip, kHID, kProj);
    conv_silu2_k<<<68 * 8, blk, 0, stream>>>(proj, conv_w, conv_b, XT, Bg, Btg, Cg);
    dt_cumsum_k<<<kNC * kH, blk, 0, stream>>>(proj, dt_bias, A_log, dtb, acum);
    states2_k<<<kNC * kH, blk, 0, stream>>>(XT, Btg, dtb, acum, states);
    scan_k<<<kH * 8, blk, 0, stream>>>(states, acum, prev);
    ssd_y4_k<<<kNC * kH * 4, blk, 0, stream>>>(Cg, Bg, XT, dtb, acum, prev, Dp, Y);
    rmsnorm_gate_k<<<kS, blk, 0, stream>>>(Y, proj, norm_w, Yb);
    cast_bf16_k<<<(kHID * kI) / 2048, blk, 0, stream>>>(W_out, Wob);
    gemm_bt_bf16<<<NtO * 16, blk, 0, stream>>>(Yb, Wob, out, kS, kHID, kI, kHID);
}

// Round 3
// 463.821 us; speedup vs baseline: 1.2681x; 1.0876x over previous
//
#include <hip/hip_runtime.h>
#include <math.h>

// Bamba-9B mixer, b=1 s=2048. Round 10: even-read 8-phase proj + split-K strip.
//  - gemm_bt_8ph: K-half staging granularity ([2kh][256][32] per buffer) so
//    ds_reads spread 10/2/10/2 per phase (was 24/8/0/0) while stages stay
//    2 gll/phase with vmcnt(6) tail. Overwrite windows re-verified: each
//    staged region's last reader drains >=1 phase before the stage issues.
//  - strip (cols 8192..8511): split-K=4 -> partials in ws + reduce kernel
//    (was a 48-block full-K kernel costing ~48us serial).
// Everything downstream unchanged.
static constexpr int kS     = 2048;
static constexpr int kHID   = 2048;
static constexpr int kI     = 4096;
static constexpr int kH     = 64;
static constexpr int kP     = 64;
static constexpr int kN     = 128;
static constexpr int kConv  = 4352;   // I + 2*G*N
static constexpr int kProj  = 8512;   // I + CONV + H
static constexpr int kChunk = 256;
static constexpr int kNC    = 8;
static constexpr float kEps = 1e-5f;

typedef __attribute__((ext_vector_type(8))) short short8;            // bf16 frag
typedef __attribute__((ext_vector_type(8))) unsigned short ushort8v;
typedef __attribute__((ext_vector_type(4))) float floatx4;

__device__ __forceinline__ float siluf(float x) {
    return x / (1.f + __expf(-x));
}
__device__ __forceinline__ unsigned short f2bf(float f) {   // RNE, finite
    unsigned int u = __float_as_uint(f);
    return (unsigned short)((u + 0x7FFFu + ((u >> 16) & 1u)) >> 16);
}
__device__ __forceinline__ float bf2f(unsigned short u) {
    return __uint_as_float((unsigned int)u << 16);
}
__device__ __forceinline__ void gll16(const void* g, void* l) {
    __builtin_amdgcn_global_load_lds(
        (const __attribute__((address_space(1))) void*)g,
        (__attribute__((address_space(3))) void*)l, 16, 0, 0);
}

// ---------- fp32 -> bf16 cast, 8 elems/thread ----------
__global__ __launch_bounds__(256)
void cast_bf16_k(const float* __restrict__ in, unsigned short* __restrict__ out)
{
    size_t i = ((size_t)blockIdx.x * 256 + threadIdx.x) * 8;
    float4 a = *(const float4*)&in[i];
    float4 b = *(const float4*)&in[i + 4];
    ushort4 u0 = {f2bf(a.x), f2bf(a.y), f2bf(a.z), f2bf(a.w)};
    ushort4 u1 = {f2bf(b.x), f2bf(b.y), f2bf(b.z), f2bf(b.w)};
    *(ushort4*)&out[i] = u0;
    *(ushort4*)&out[i + 4] = u1;
}

// ---------- 256x256-tile 8-phase bf16 NT GEMM (proj main, N%256==0) --------
// Buffers: [2 kh][256 rows][32 shorts] (32KB each of A0s/B0s/A1s/B1s).
// Phase reads 10/2/10/2 ds_read_b128 feeding that phase's 16-MFMA cluster;
// 2 gll16 staged per phase; vmcnt(6) once per K-tile.
// Stage map for group(tile t, bufs P): S1=B(t+1)kh1 into Pbar (freed by
// group(t-1) ph3/4); S2=A(t+2)kh0 into P (a0 read ph1); S3=B(t+2)kh0 into P
// (b·k0 read ph1/2); S4=A(t+2)kh1 into P (a1 read ph3). Tail vmcnt(6) leaves
// group's S2-S4 (tile t+2) in flight, completes S1 (needed 2 phases later).
#define MF16(acc_, a_, b_) \
    acc_ = __builtin_amdgcn_mfma_f32_16x16x32_bf16(a_, b_, acc_, 0, 0, 0)

#define PH_TOP()                                               \
    __builtin_amdgcn_s_barrier();                              \
    asm volatile("s_waitcnt lgkmcnt(0)" ::: "memory");         \
    __builtin_amdgcn_s_setprio(1);

#define PH_BOT()                                               \
    __builtin_amdgcn_s_setprio(0);                             \
    __builtin_amdgcn_s_barrier();

#define GROUP(LA, LB, S1, S2, S3, S4, VMTAIL)                                  \
    {                                                                          \
        short8 a0[8], a1[8], b0, b1, b2, b3;                                   \
        _Pragma("unroll")                                                      \
        for (int m = 0; m < 8; ++m)                                            \
            a0[m] = *(const short8*)&(LA)[aoff2 + (m << 9)];                   \
        b0 = *(const short8*)&(LB)[boff2];                                     \
        b1 = *(const short8*)&(LB)[boff2 + (1 << 9)];                          \
        S1;                                                                    \
        PH_TOP();                                                              \
        _Pragma("unroll")                                                      \
        for (int m = 0; m < 8; ++m) {                                          \
            MF16(acc[m][0], a0[m], b0);                                        \
            MF16(acc[m][1], a0[m], b1);                                        \
        }                                                                      \
        PH_BOT();                                                              \
        b2 = *(const short8*)&(LB)[boff2 + (2 << 9)];                          \
        b3 = *(const short8*)&(LB)[boff2 + (3 << 9)];                          \
        S2;                                                                    \
        PH_TOP();                                                              \
        _Pragma("unroll")                                                      \
        for (int m = 0; m < 8; ++m) {                                          \
            MF16(acc[m][2], a0[m], b2);                                        \
            MF16(acc[m][3], a0[m], b3);                                        \
        }                                                                      \
        PH_BOT();                                                              \
        _Pragma("unroll")                                                      \
        for (int m = 0; m < 8; ++m)                                            \
            a1[m] = *(const short8*)&(LA)[8192 + aoff2 + (m << 9)];            \
        b0 = *(const short8*)&(LB)[8192 + boff2];                              \
        b1 = *(const short8*)&(LB)[8192 + boff2 + (1 << 9)];                   \
        S3;                                                                    \
        PH_TOP();                                                              \
        _Pragma("unroll")                                                      \
        for (int m = 0; m < 8; ++m) {                                          \
            MF16(acc[m][0], a1[m], b0);                                        \
            MF16(acc[m][1], a1[m], b1);                                        \
        }                                                                      \
        PH_BOT();                                                              \
        b2 = *(const short8*)&(LB)[8192 + boff2 + (2 << 9)];                   \
        b3 = *(const short8*)&(LB)[8192 + boff2 + (3 << 9)];                   \
        S4;                                                                    \
        PH_TOP();                                                              \
        _Pragma("unroll")                                                      \
        for (int m = 0; m < 8; ++m) {                                          \
            MF16(acc[m][2], a1[m], b2);                                        \
            MF16(acc[m][3], a1[m], b3);                                        \
        }                                                                      \
        __builtin_amdgcn_s_setprio(0);                                         \
        VMTAIL;                                                                \
        __builtin_amdgcn_s_barrier();                                          \
    }

__global__ __launch_bounds__(512)
void gemm_bt_8ph(const unsigned short* __restrict__ A,
                 const unsigned short* __restrict__ B,
                 float* __restrict__ C, int M, int N, int K, int ldc)
{
    __shared__ __attribute__((aligned(16))) unsigned short A0s[16384];
    __shared__ __attribute__((aligned(16))) unsigned short B0s[16384];
    __shared__ __attribute__((aligned(16))) unsigned short A1s[16384];
    __shared__ __attribute__((aligned(16))) unsigned short B1s[16384];
    const int tid = threadIdx.x;
    const int lane = tid & 63, wave = tid >> 6;
    const int quad = lane >> 4, l15 = lane & 15;
    const int wm = wave >> 2, wn = wave & 3;

    // bijective XCD swizzle (m204), nt-major / mt-fast.
    const int Mt = M >> 8, Nt = N >> 8;
    const int nwg = Mt * Nt;
    const int q = nwg >> 3, r = nwg & 7;
    const int xcd = blockIdx.x & 7, idx = blockIdx.x >> 3;
    const int wgid = (xcd < r ? xcd * (q + 1) : r * (q + 1) + (xcd - r) * q) + idx;
    const int mt = wgid % Mt, nt = wgid / Mt;
    const int m0 = mt << 8, n0 = nt << 8;

    // stage one 16KB K-half: 1024 chunks of 16B; phys chunk c holds logical
    // k-chunk c^(row&3) (pre-swizzled source, linear LDS dest).
    auto stA = [&](unsigned short* arr, int t, int kh) {
        const int kb = (t << 6) + (kh << 5);
#pragma unroll
        for (int i = 0; i < 2; ++i) {
            const int f = tid + (i << 9);
            const int rr = f >> 2, lc = (f & 3) ^ (rr & 3);
            gll16(&A[(size_t)(m0 + rr) * K + kb + (lc << 3)],
                  &arr[(kh << 13) + ((size_t)f << 3)]);
        }
    };
    auto stB = [&](unsigned short* arr, int t, int kh) {
        const int kb = (t << 6) + (kh << 5);
#pragma unroll
        for (int i = 0; i < 2; ++i) {
            const int f = tid + (i << 9);
            const int rr = f >> 2, lc = (f & 3) ^ (rr & 3);
            gll16(&B[(size_t)(n0 + rr) * K + kb + (lc << 3)],
                  &arr[(kh << 13) + ((size_t)f << 3)]);
        }
    };

    floatx4 acc[8][4] = {};

    const int ph = quad ^ (l15 & 3);                       // phys chunk on read
    const int aoff2 = ((wm << 7) + l15) * 32 + (ph << 3);  // shorts
    const int boff2 = ((wn << 6) + l15) * 32 + (ph << 3);

    // prologue: t0 full (8 gll) then t1 {Akh0,Bkh0,Akh1} (6 gll).
    stA(A0s, 0, 0); stB(B0s, 0, 0); stA(A0s, 0, 1); stB(B0s, 0, 1);
    stA(A1s, 1, 0); stB(B1s, 1, 0); stA(A1s, 1, 1);
    asm volatile("s_waitcnt vmcnt(6)" ::: "memory");
    __builtin_amdgcn_s_barrier();

    const int NITER = K >> 7;   // tile pairs
    for (int it = 0; it < NITER; ++it) {
        const int t = it << 1;
        const bool nl = (it + 1 < NITER);
        // group A: tile t (A0s,B0s)
        GROUP(A0s, B0s,
              stB(B1s, t + 1, 1),
              if (nl) stA(A0s, t + 2, 0),
              if (nl) stB(B0s, t + 2, 0),
              if (nl) stA(A0s, t + 2, 1),
              if (nl) asm volatile("s_waitcnt vmcnt(6)" ::: "memory");
              else    asm volatile("s_waitcnt vmcnt(0)" ::: "memory"))
        // group B: tile t+1 (A1s,B1s)
        GROUP(A1s, B1s,
              if (nl) stB(B0s, t + 2, 1),
              if (nl) stA(A1s, t + 3, 0),
              if (nl) stB(B1s, t + 3, 0),
              if (nl) stA(A1s, t + 3, 1),
              if (nl) asm volatile("s_waitcnt vmcnt(6)" ::: "memory");
              else    asm volatile("s_waitcnt vmcnt(0)" ::: "memory"))
    }

#pragma unroll
    for (int m = 0; m < 8; ++m) {
        const int row = m0 + (wm << 7) + m * 16 + (quad << 2);
#pragma unroll
        for (int n = 0; n < 4; ++n) {
            const int col = n0 + (wn << 6) + n * 16 + l15;
#pragma unroll
            for (int rr = 0; rr < 4; ++rr)
                C[(size_t)(row + rr) * ldc + col] = acc[m][n][rr];
        }
    }
}

// ---------- bf16 MFMA NT GEMM (128^2 m97 structure; out GEMM) ----------
__global__ __launch_bounds__(256)
void gemm_bt_bf16(const unsigned short* __restrict__ A,
                  const unsigned short* __restrict__ B,
                  float* __restrict__ C, int M, int N, int K, int ldc)
{
    __shared__ unsigned short As[128 * 64];
    __shared__ unsigned short Bs[128 * 64];
    const int tid = threadIdx.x;
    const int lane = tid & 63, quad = lane >> 4, l15 = lane & 15;
    const int wave = tid >> 6;

    const int Nt = (N + 127) >> 7;
    const int mainN = Nt & ~7;
    int bi = blockIdx.x, mt, nt;
    if (bi < mainN * 16) {
        nt = ((bi >> 7) << 3) | (bi & 7);
        mt = (bi >> 3) & 15;
    } else {
        int r = bi - mainN * 16, rem = Nt - mainN;
        nt = mainN + r % rem; mt = r / rem;
    }
    const int m0 = mt * 128, n0 = nt * 128;
    const int wm = (wave & 1) * 64, wn = (wave >> 1) * 64;

    floatx4 acc[4][4] = {};

    int rowS[4], lcS[4];
#pragma unroll
    for (int i = 0; i < 4; ++i) {
        int f = tid + 256 * i;
        rowS[i] = f >> 3;
        lcS[i] = ((f & 7) ^ (rowS[i] & 7)) * 8;
    }

    for (int k0 = 0; k0 < K; k0 += 64) {
#pragma unroll
        for (int i = 0; i < 4; ++i) {
            int ra = m0 + rowS[i];
            gll16(&A[(size_t)ra * K + k0 + lcS[i]], &As[(size_t)(tid + 256 * i) * 8]);
        }
#pragma unroll
        for (int i = 0; i < 4; ++i) {
            int rb = n0 + rowS[i]; if (rb > N - 1) rb = N - 1;
            gll16(&B[(size_t)rb * K + k0 + lcS[i]], &Bs[(size_t)(tid + 256 * i) * 8]);
        }
        __syncthreads();

        short8 af[4][2], bf[4][2];
#pragma unroll
        for (int ks = 0; ks < 2; ++ks) {
            const int ph = ((ks * 4 + quad) ^ (l15 & 7)) * 8;
#pragma unroll
            for (int mi = 0; mi < 4; ++mi)
                af[mi][ks] = *(const short8*)&As[(size_t)(wm + mi * 16 + l15) * 64 + ph];
#pragma unroll
            for (int ni = 0; ni < 4; ++ni)
                bf[ni][ks] = *(const short8*)&Bs[(size_t)(wn + ni * 16 + l15) * 64 + ph];
        }
#pragma unroll
        for (int ks = 0; ks < 2; ++ks)
#pragma unroll
            for (int mi = 0; mi < 4; ++mi)
#pragma unroll
                for (int ni = 0; ni < 4; ++ni)
                    acc[mi][ni] = __builtin_amdgcn_mfma_f32_16x16x32_bf16(
                        af[mi][ks], bf[ni][ks], acc[mi][ni], 0, 0, 0);
        __syncthreads();
    }

#pragma unroll
    for (int mi = 0; mi < 4; ++mi)
#pragma unroll
        for (int ni = 0; ni < 4; ++ni) {
            int col = n0 + wn + ni * 16 + l15;
            if (col < N) {
#pragma unroll
                for (int r = 0; r < 4; ++r) {
                    int row = m0 + wm + mi * 16 + quad * 4 + r;
                    C[(size_t)row * ldc + col] = acc[mi][ni][r];
                }
            }
        }
}

// ---------- strip GEMM (cols 8192..8511), split-K=4 -> partials ----------
// grid: sk(4) x mt(16) x nt(3); B passed pre-offset to strip rows (320 rows).
__global__ __launch_bounds__(256)
void gemm_strip_sk(const unsigned short* __restrict__ A,
                   const unsigned short* __restrict__ B,
                   float* __restrict__ P, int K)
{
    __shared__ unsigned short As[128 * 64];
    __shared__ unsigned short Bs[128 * 64];
    const int bi = blockIdx.x;
    const int sk = bi / 48, rem = bi % 48, mt = rem / 3, nt = rem % 3;
    const int m0 = mt * 128, n0 = nt * 128, kbase = sk * 512;
    const int tid = threadIdx.x;
    const int lane = tid & 63, quad = lane >> 4, l15 = lane & 15;
    const int wave = tid >> 6;
    const int wm = (wave & 1) * 64, wn = (wave >> 1) * 64;

    floatx4 acc[4][4] = {};

    int rowS[4], lcS[4];
#pragma unroll
    for (int i = 0; i < 4; ++i) {
        int f = tid + 256 * i;
        rowS[i] = f >> 3;
        lcS[i] = ((f & 7) ^ (rowS[i] & 7)) * 8;
    }

    for (int kk = 0; kk < 512; kk += 64) {
        const int k0 = kbase + kk;
#pragma unroll
        for (int i = 0; i < 4; ++i) {
            int ra = m0 + rowS[i];
            gll16(&A[(size_t)ra * K + k0 + lcS[i]], &As[(size_t)(tid + 256 * i) * 8]);
        }
#pragma unroll
        for (int i = 0; i < 4; ++i) {
            int rb = n0 + rowS[i]; if (rb > 319) rb = 319;
            gll16(&B[(size_t)rb * K + k0 + lcS[i]], &Bs[(size_t)(tid + 256 * i) * 8]);
        }
        __syncthreads();

        short8 af[4][2], bf[4][2];
#pragma unroll
        for (int ks = 0; ks < 2; ++ks) {
            const int ph = ((ks * 4 + quad) ^ (l15 & 7)) * 8;
#pragma unroll
            for (int mi = 0; mi < 4; ++mi)
                af[mi][ks] = *(const short8*)&As[(size_t)(wm + mi * 16 + l15) * 64 + ph];
#pragma unroll
            for (int ni = 0; ni < 4; ++ni)
                bf[ni][ks] = *(const short8*)&Bs[(size_t)(wn + ni * 16 + l15) * 64 + ph];
        }
#pragma unroll
        for (int ks = 0; ks < 2; ++ks)
#pragma unroll
            for (int mi = 0; mi < 4; ++mi)
#pragma unroll
                for (int ni = 0; ni < 4; ++ni)
                    acc[mi][ni] = __builtin_amdgcn_mfma_f32_16x16x32_bf16(
                        af[mi][ks], bf[ni][ks], acc[mi][ni], 0, 0, 0);
        __syncthreads();
    }

    float* Po = P + (size_t)sk * kS * 320;
#pragma unroll
    for (int mi = 0; mi < 4; ++mi)
#pragma unroll
        for (int ni = 0; ni < 4; ++ni) {
            int col = n0 + wn + ni * 16 + l15;
            if (col < 320) {
#pragma unroll
                for (int r = 0; r < 4; ++r) {
                    int row = m0 + wm + mi * 16 + quad * 4 + r;
                    Po[(size_t)row * 320 + col] = acc[mi][ni][r];
                }
            }
        }
}

// ---------- strip reduce: proj[:,8192+n] = sum_sk P[sk] ----------
__global__ __launch_bounds__(256)
void strip_reduce_k(const float* __restrict__ P, float* __restrict__ proj)
{
    const size_t i = ((size_t)blockIdx.x * 256 + threadIdx.x) * 4;
    const size_t stride = (size_t)kS * 320;
    float4 s0 = *(const float4*)&P[i];
    float4 s1 = *(const float4*)&P[i + stride];
    float4 s2 = *(const float4*)&P[i + 2 * stride];
    float4 s3 = *(const float4*)&P[i + 3 * stride];
    float4 o;
    o.x = s0.x + s1.x + s2.x + s3.x;
    o.y = s0.y + s1.y + s2.y + s3.y;
    o.z = s0.z + s1.z + s2.z + s3.z;
    o.w = s0.w + s1.w + s2.w + s3.w;
    const int m = (int)(i / 320), n = (int)(i % 320);
    *(float4*)&proj[(size_t)m * kProj + 8192 + n] = o;
}

// ---------- conv+SiLU -> bf16 consumer layouts ----------
__global__ __launch_bounds__(256)
void conv_silu2_k(const float* __restrict__ proj, const float* __restrict__ cw,
                  const float* __restrict__ cb,
                  unsigned short* __restrict__ XT, unsigned short* __restrict__ Bg,
                  unsigned short* __restrict__ Btg, unsigned short* __restrict__ Cg)
{
    __shared__ __attribute__((aligned(16))) unsigned short T[64][264];
    const int bd = blockIdx.x % 68, bt = blockIdx.x / 68;
    const int d0 = bd * 64, t0 = bt * 256;
    const int tid = threadIdx.x;
    const int dl = tid & 63;
    const int d = d0 + dl;
    const float b0 = cb[d];
    const float w0 = cw[d * 4 + 0], w1 = cw[d * 4 + 1];
    const float w2 = cw[d * 4 + 2], w3 = cw[d * 4 + 3];
    for (int it = 0; it < 64; ++it) {
        int tl = it * 4 + (tid >> 6);
        int t = t0 + tl;
        const float* pc = &proj[(size_t)t * kProj + kI + d];
        float acc = b0 + w3 * pc[0];
        if (t >= 1) acc += w2 * pc[-(ptrdiff_t)kProj];
        if (t >= 2) acc += w1 * pc[-(ptrdiff_t)(2 * kProj)];
        if (t >= 3) acc += w0 * pc[-(ptrdiff_t)(3 * kProj)];
        T[dl][tl] = f2bf(siluf(acc));
    }
    __syncthreads();

    if (d0 < kI) {                       // X: XT[d][t], rows along t (coalesced)
        int row = tid >> 2, cg = (tid & 3) * 64;
#pragma unroll
        for (int j = 0; j < 8; ++j)
            *(ushort8v*)&XT[(size_t)(d0 + row) * kS + t0 + cg + j * 8] =
                *(const ushort8v*)&T[row][cg + j * 8];
    } else if (d0 < kI + kN) {           // B: Bt[n][t] + Bg[t][n]
        int n0 = d0 - kI;
        int row = tid >> 2, cg = (tid & 3) * 64;
#pragma unroll
        for (int j = 0; j < 8; ++j)
            *(ushort8v*)&Btg[(size_t)(n0 + row) * kS + t0 + cg + j * 8] =
                *(const ushort8v*)&T[row][cg + j * 8];
        for (int pass = 0; pass < 16; ++pass) {
            int tl = pass * 16 + (tid >> 4), nq = (tid & 15) * 4;
            ushort4 v = {T[nq][tl], T[nq + 1][tl], T[nq + 2][tl], T[nq + 3][tl]};
            *(ushort4*)&Bg[(size_t)(t0 + tl) * kN + n0 + nq] = v;
        }
    } else {                             // C: Cg[t][n]
        int n0 = d0 - (kI + kN);
        for (int pass = 0; pass < 16; ++pass) {
            int tl = pass * 16 + (tid >> 4), nq = (tid & 15) * 4;
            ushort4 v = {T[nq][tl], T[nq + 1][tl], T[nq + 2][tl], T[nq + 3][tl]};
            *(ushort4*)&Cg[(size_t)(t0 + tl) * kN + n0 + nq] = v;
        }
    }
}

// ---------- dt = softplus(proj_dt + bias); per-chunk cumsum(dt*A) ----------
__global__ __launch_bounds__(256)
void dt_cumsum_k(const float* __restrict__ proj, const float* __restrict__ dt_bias,
                 const float* __restrict__ A_log, float* __restrict__ dt,
                 float* __restrict__ acum)
{
    __shared__ float wsum[4];
    const int c = blockIdx.x >> 6, h = blockIdx.x & 63;
    const int l = threadIdx.x, t = c * kChunk + l;
    float a = -expf(A_log[h]);
    float z = proj[(size_t)t * kProj + kI + kConv + h] + dt_bias[h];
    float d = (z > 20.f) ? z : log1pf(expf(z));
    dt[t * kH + h] = d;
    float v = d * a;
    int lane = l & 63, w = l >> 6;
#pragma unroll
    for (int off = 1; off < 64; off <<= 1) {
        float u = __shfl_up(v, off);
        if (lane >= off) v += u;
    }
    if (lane == 63) wsum[w] = v;
    __syncthreads();
    float add = 0.f;
    for (int i = 0; i < w; ++i) add += wsum[i];
    acum[t * kH + h] = v + add;
}

// ---------- states (v2): bf16 MFMA. out[p][n] = sum_s Xw^T[p][s] Bt[n][s] ---
__global__ __launch_bounds__(256)
void states2_k(const unsigned short* __restrict__ XT,
               const unsigned short* __restrict__ Btg,
               const float* __restrict__ dt, const float* __restrict__ acum,
               float* __restrict__ states)
{
    __shared__ __attribute__((aligned(16))) unsigned short Aw[64 * 72];
    __shared__ __attribute__((aligned(16))) unsigned short Bs[128 * 64];
    __shared__ float Wl[256];
    const int c = blockIdx.x >> 6, h = blockIdx.x & 63;
    const int tid = threadIdx.x;
    const int wave = tid >> 6, lane = tid & 63;
    const int quad = lane >> 4, l15 = lane & 15;
    const float aend = acum[(size_t)(c * kChunk + 255) * kH + h];
    {
        int t = c * kChunk + tid;
        Wl[tid] = __expf(aend - acum[(size_t)t * kH + h]) * dt[(size_t)t * kH + h];
    }
    __syncthreads();

    floatx4 acc[4][2] = {};
    for (int lt = 0; lt < 4; ++lt) {
        const int s0 = c * kChunk + lt * 64;
#pragma unroll
        for (int i = 0; i < 2; ++i) {       // Aw[p][s] = XT * w, stride 72
            int f = tid + 256 * i;
            int p = f >> 3, sc = (f & 7) * 8;
            ushort8v xv = *(const ushort8v*)&XT[(size_t)(h * 64 + p) * kS + s0 + sc];
            ushort8v o;
#pragma unroll
            for (int j = 0; j < 8; ++j)
                o[j] = f2bf(bf2f(xv[j]) * Wl[lt * 64 + sc + j]);
            *(ushort8v*)&Aw[p * 72 + sc] = o;
        }
#pragma unroll
        for (int i = 0; i < 4; ++i) {       // Bs[n][s], phys chunk = lg ^ (n&7)
            int f = tid + 256 * i;
            int n = f >> 3, ph = f & 7, lg = ph ^ (n & 7);
            gll16(&Btg[(size_t)n * kS + s0 + lg * 8], &Bs[(size_t)f * 8]);
        }
        __syncthreads();
#pragma unroll
        for (int ks = 0; ks < 2; ++ks) {
            short8 bfr[2];
#pragma unroll
            for (int nj = 0; nj < 2; ++nj) {
                int n = (wave * 2 + nj) * 16 + l15;
                int ph = (ks * 4 + quad) ^ (n & 7);
                bfr[nj] = *(const short8*)&Bs[n * 64 + ph * 8];
            }
#pragma unroll
            for (int pi = 0; pi < 4; ++pi) {
                short8 af = *(const short8*)&Aw[(pi * 16 + l15) * 72 + ks * 32 + quad * 8];
                acc[pi][0] = __builtin_amdgcn_mfma_f32_16x16x32_bf16(af, bfr[0], acc[pi][0], 0, 0, 0);
                acc[pi][1] = __builtin_amdgcn_mfma_f32_16x16x32_bf16(af, bfr[1], acc[pi][1], 0, 0, 0);
            }
        }
        __syncthreads();
    }
    const size_t base = (size_t)(c * kH + h) * (kP * kN);
#pragma unroll
    for (int pi = 0; pi < 4; ++pi)
#pragma unroll
        for (int nj = 0; nj < 2; ++nj) {
            int n = (wave * 2 + nj) * 16 + l15;
#pragma unroll
            for (int r = 0; r < 4; ++r)
                states[base + (size_t)(pi * 16 + quad * 4 + r) * kN + n] = acc[pi][nj][r];
        }
}

// ---------- sequential inter-chunk recurrence ----------
__global__ __launch_bounds__(256)
void scan_k(const float* __restrict__ states, const float* __restrict__ acum,
            float* __restrict__ prev)
{
    const int h = blockIdx.x >> 3, seg = blockIdx.x & 7;
    const int e = (seg * 256 + threadIdx.x) * 4;
    float4 carry = make_float4(0.f, 0.f, 0.f, 0.f);
    for (int c = 0; c < kNC; ++c) {
        size_t base = (size_t)(c * kH + h) * (kP * kN);
        *(float4*)&prev[base + e] = carry;
        float dec = __expf(acum[(size_t)(c * kChunk + 255) * kH + h]);
        float4 st = *(const float4*)&states[base + e];
        carry.x = carry.x * dec + st.x; carry.y = carry.y * dec + st.y;
        carry.z = carry.z * dec + st.z; carry.w = carry.w * dec + st.w;
    }
}

// ---------- SSD Y (v4): gll16-staged bf16 tiles, XOR-swizzled ----------
__global__ __launch_bounds__(256)
void ssd_y4_k(const unsigned short* __restrict__ Cg,
              const unsigned short* __restrict__ Bg,
              const unsigned short* __restrict__ XT,
              const float* __restrict__ dt, const float* __restrict__ acum,
              const float* __restrict__ prev, const float* __restrict__ Dp,
              float* __restrict__ Y)
{
    __shared__ __attribute__((aligned(16))) unsigned short Cb[64 * 128];
    __shared__ __attribute__((aligned(16))) unsigned short Bb[64 * 128];
    __shared__ __attribute__((aligned(16))) unsigned short Xt[64 * 64];
    __shared__ __attribute__((aligned(16))) unsigned short Wb[64 * 72];
    __shared__ float At[64], Asv[64], Dtv[64];

    const int bi = blockIdx.x;
    const int ti = bi & 3, h = (bi >> 2) & 63, c = bi >> 8;
    const int tid = threadIdx.x;
    const int wave = tid >> 6, lane = tid & 63;
    const int quad = lane >> 4, l15 = lane & 15;
    const int trow0 = c * kChunk + ti * 64;
    const float Dh = Dp[h];

#pragma unroll
    for (int i = 0; i < 4; ++i) {
        int f = tid + 256 * i;
        int row = f >> 4, ph = f & 15, lg = ph ^ (row & 15);
        gll16(&Cg[(size_t)(trow0 + row) * kN + lg * 8], &Cb[(size_t)f * 8]);
    }
    const size_t pbase = (size_t)(c * kH + h) * (kP * kN);
#pragma unroll
    for (int r = 0; r < 8; ++r) {
        int f = tid + 256 * r;
        int row = f >> 5, c4 = (f & 31) * 4;          // 4 fp32 = half a 16B chunk
        float4 v = *(const float4*)&prev[pbase + (size_t)row * kN + c4];
        ushort4 u = {f2bf(v.x), f2bf(v.y), f2bf(v.z), f2bf(v.w)};
        int dst = row * 128 + ((((f & 31) >> 1) ^ (row & 15)) * 8) + (f & 1) * 4;
        *(ushort4*)&Bb[dst] = u;
    }
    if (tid < 64) At[tid] = acum[(size_t)(trow0 + tid) * kH + h];
    __syncthreads();

    floatx4 yacc[4] = {};
#pragma unroll
    for (int ks = 0; ks < 4; ++ks) {
        int cha = (ks * 4 + quad) ^ l15;
        short8 a = *(const short8*)&Cb[(wave * 16 + l15) * 128 + cha * 8];
#pragma unroll
        for (int ni = 0; ni < 4; ++ni) {
            short8 b = *(const short8*)&Bb[(ni * 16 + l15) * 128 + cha * 8];
            yacc[ni] = __builtin_amdgcn_mfma_f32_16x16x32_bf16(a, b, yacc[ni], 0, 0, 0);
        }
    }
    {
        float eAr[4];
#pragma unroll
        for (int r = 0; r < 4; ++r) eAr[r] = __expf(At[wave * 16 + quad * 4 + r]);
#pragma unroll
        for (int ni = 0; ni < 4; ++ni)
#pragma unroll
            for (int r = 0; r < 4; ++r) yacc[ni][r] *= eAr[r];
    }

    for (int si = 0; si <= ti; ++si) {
        const int srow0 = c * kChunk + si * 64;
        __syncthreads();
#pragma unroll
        for (int i = 0; i < 4; ++i) {       // B tile
            int f = tid + 256 * i;
            int row = f >> 4, ph = f & 15, lg = ph ^ (row & 15);
            gll16(&Bg[(size_t)(srow0 + row) * kN + lg * 8], &Bb[(size_t)f * 8]);
        }
#pragma unroll
        for (int i = 0; i < 2; ++i) {       // X^T tile [p][s]
            int f = tid + 256 * i;
            int p = f >> 3, ph = f & 7, lg = ph ^ (p & 7);
            gll16(&XT[(size_t)(h * 64 + p) * kS + srow0 + lg * 8], &Xt[(size_t)f * 8]);
        }
        if (tid < 64) {
            Asv[tid] = acum[(size_t)(srow0 + tid) * kH + h];
            Dtv[tid] = dt[(size_t)(srow0 + tid) * kH + h];
        }
        __syncthreads();

        floatx4 sacc[4] = {};
#pragma unroll
        for (int ks = 0; ks < 4; ++ks) {
            int cha = (ks * 4 + quad) ^ l15;
            short8 a = *(const short8*)&Cb[(wave * 16 + l15) * 128 + cha * 8];
#pragma unroll
            for (int ni = 0; ni < 4; ++ni) {
                short8 b = *(const short8*)&Bb[(ni * 16 + l15) * 128 + cha * 8];
                sacc[ni] = __builtin_amdgcn_mfma_f32_16x16x32_bf16(a, b, sacc[ni], 0, 0, 0);
            }
        }

        const bool diag = (si == ti);
#pragma unroll
        for (int ni = 0; ni < 4; ++ni) {
            int s_ = ni * 16 + l15;
            float as = Asv[s_], dts = Dtv[s_];
#pragma unroll
            for (int r = 0; r < 4; ++r) {
                int tl = wave * 16 + quad * 4 + r;
                float w = sacc[ni][r] * __expf(At[tl] - as) * dts;
                if (diag) {
                    if (s_ > tl) w = 0.f;
                    else if (s_ == tl) w += Dh;
                }
                Wb[tl * 72 + s_] = f2bf(w);
            }
        }
#pragma unroll
        for (int ks = 0; ks < 2; ++ks) {
            short8 aw = *(const short8*)&Wb[(wave * 16 + l15) * 72 + ks * 32 + quad * 8];
#pragma unroll
            for (int ni = 0; ni < 4; ++ni) {
                int ph = ((ks * 4 + quad) ^ (l15 & 7)) * 8;
                short8 xb = *(const short8*)&Xt[(ni * 16 + l15) * 64 + ph];
                yacc[ni] = __builtin_amdgcn_mfma_f32_16x16x32_bf16(aw, xb, yacc[ni], 0, 0, 0);
            }
        }
    }

#pragma unroll
    for (int ni = 0; ni < 4; ++ni)
#pragma unroll
        for (int r = 0; r < 4; ++r)
            Y[(size_t)(trow0 + wave * 16 + quad * 4 + r) * kI + h * kP + ni * 16 + l15]
                = yacc[ni][r];
}

// ---------- gated RMSNorm -> bf16 ----------
__global__ __launch_bounds__(256)
void rmsnorm_gate_k(const float* __restrict__ Y, const float* __restrict__ proj,
                    const float* __restrict__ nw, unsigned short* __restrict__ Yb)
{
    __shared__ float red[4];
    const int t = blockIdx.x, tid = threadIdx.x;
    const float* yrow = &Y[(size_t)t * kI];
    const float* grow = &proj[(size_t)t * kProj];
    float v[16];
    float ss = 0.f;
#pragma unroll
    for (int j = 0; j < 4; ++j) {
        int i = (tid + 256 * j) * 4;
        float4 y4 = *(const float4*)&yrow[i];
        float4 g4 = *(const float4*)&grow[i];
        float a = y4.x * siluf(g4.x), bq = y4.y * siluf(g4.y);
        float cq = y4.z * siluf(g4.z), d = y4.w * siluf(g4.w);
        v[j * 4 + 0] = a; v[j * 4 + 1] = bq; v[j * 4 + 2] = cq; v[j * 4 + 3] = d;
        ss += a * a + bq * bq + cq * cq + d * d;
    }
#pragma unroll
    for (int off = 32; off > 0; off >>= 1) ss += __shfl_down(ss, off);
    if ((tid & 63) == 0) red[tid >> 6] = ss;
    __syncthreads();
    float sum = red[0] + red[1] + red[2] + red[3];
    float rr = rsqrtf(sum * (1.f / kI) + kEps);
#pragma unroll
    for (int j = 0; j < 4; ++j) {
        int i = (tid + 256 * j) * 4;
        float4 w4 = *(const float4*)&nw[i];
        ushort4 o;
        o.x = f2bf(v[j * 4 + 0] * rr * w4.x);
        o.y = f2bf(v[j * 4 + 1] * rr * w4.y);
        o.z = f2bf(v[j * 4 + 2] * rr * w4.z);
        o.w = f2bf(v[j * 4 + 3] * rr * w4.w);
        *(ushort4*)&Yb[(size_t)t * kI + i] = o;
    }
}

extern "C" void kernel_launch(void* const* d_in, const int* in_sizes, int n_in,
                              void* d_out, int out_size, void* d_ws, size_t ws_size,
                              hipStream_t stream)
{
    const float* x       = (const float*)d_in[0];
    const float* W_in    = (const float*)d_in[1];
    const float* conv_w  = (const float*)d_in[2];
    const float* conv_b  = (const float*)d_in[3];
    const float* dt_bias = (const float*)d_in[4];
    const float* A_log   = (const float*)d_in[5];
    const float* Dp      = (const float*)d_in[6];
    const float* norm_w  = (const float*)d_in[7];
    const float* W_out   = (const float*)d_in[8];
    float* out = (float*)d_out;

    float* ws   = (float*)d_ws;
    float* proj = ws;                                       // 2048*8512 f
    unsigned short* XT  = (unsigned short*)(proj + (size_t)kS * kProj);  // 4096*2048
    unsigned short* Bg  = XT + (size_t)kI * kS;             // 2048*128
    unsigned short* Btg = Bg + (size_t)kS * kN;             // 128*2048
    unsigned short* Cg  = Btg + (size_t)kN * kS;            // 2048*128
    float* dtb  = (float*)(Cg + (size_t)kS * kN);           // 2048*64
    float* acum = dtb + (size_t)kS * kH;                    // 2048*64
    float* prev = acum + (size_t)kS * kH;                   // 4,194,304 f
    float* Y    = prev + (size_t)kNC * kH * kP * kN;        // 8,388,608 f
    float* states = Y;
    unsigned short* xb  = XT;                               // early alias
    unsigned short* Wb  = (unsigned short*)prev;            // early (spans into Y)
    unsigned short* Yb  = (unsigned short*)prev;            // late
    unsigned short* Wob = XT;                               // late
    // strip partials: after Wb's float-equivalent footprint (8512*2048/2 f),
    // still inside prev+Y region (needs 2,621,440 f; 8,716,288+2,621,440 <
    // 12,582,912). Freed before states2 writes states/Y.
    float* Pstrip = prev + ((size_t)kProj * kHID) / 2;

    dim3 blk(256);
    const int NtO = kHID / 128;            // 16
    const int kNmain = 8192;               // 32 x 256-col tiles -> 256 blocks
    cast_bf16_k<<<(kS * kHID) / 2048, blk, 0, stream>>>(x, xb);
    cast_bf16_k<<<(kProj * kHID) / 2048, blk, 0, stream>>>(W_in, Wb);
    gemm_bt_8ph<<<(kS >> 8) * (kNmain >> 8), dim3(512), 0, stream>>>(
        xb, Wb, proj, kS, kNmain, kHID, kProj);
    gemm_strip_sk<<<192, blk, 0, stream>>>(
        xb, Wb + (size_t)kNmain * kHID, Pstrip, kHID);
    strip_reduce_k<<<(kS * 320) / 1024, blk, 0, stream>>>(Pstrip, proj);
    conv_silu2_k<<<68 * 8, blk, 0, stream>>>(proj, conv_w, conv_b, XT, Bg, Btg, Cg);
    dt_cumsum_k<<<kNC * kH, blk, 0, stream>>>(proj, dt_bias, A_log, dtb, acum);
    states2_k<<<kNC * kH, blk, 0, stream>>>(XT, Btg, dtb, acum, states);
    scan_k<<<kH * 8, blk, 0, stream>>>(states, acum, prev);
    ssd_y4_k<<<kNC * kH * 4, blk, 0, stream>>>(Cg, Bg, XT, dtb, acum, prev, Dp, Y);
    rmsnorm_gate_k<<<kS, blk, 0, stream>>>(Y, proj, norm_w, Yb);
    cast_bf16_k<<<(kHID * kI) / 2048, blk, 0, stream>>>(W_out, Wob);
    gemm_bt_bf16<<<NtO * 16, blk, 0, stream>>>(Yb, Wob, out, kS, kHID, kI, kHID);
}

// Round 4
// 440.047 us; speedup vs baseline: 1.3367x; 1.0540x over previous
//
#include <hip/hip_runtime.h>
#include <math.h>

// Bamba-9B mixer, b=1 s=2048. Round 11: out GEMM -> 8-phase 256^2 + split-K=4.
//  - Round-10 counters: out GEMM (128^2 m97, 256 blocks = 1/CU) was the top
//    dispatch at 85us / 405 TF / MfmaUtil 15.5% — the m97 structure needs
//    multi-block-per-CU overlap, which a 256-tile grid can't provide.
//  - gemm_bt_8ph generalized (lda + grid-derived split-K): proj main unchanged
//    (sk=0); out GEMM = 4 splits x 64 tiles = 256 blocks, K=1024 each, fp32
//    partials in the proj region (dead after rmsnorm), 4-way reduce -> out.
//  - 128^2 m97 kernel deleted (unused).
static constexpr int kS     = 2048;
static constexpr int kHID   = 2048;
static constexpr int kI     = 4096;
static constexpr int kH     = 64;
static constexpr int kP     = 64;
static constexpr int kN     = 128;
static constexpr int kConv  = 4352;   // I + 2*G*N
static constexpr int kProj  = 8512;   // I + CONV + H
static constexpr int kChunk = 256;
static constexpr int kNC    = 8;
static constexpr float kEps = 1e-5f;

typedef __attribute__((ext_vector_type(8))) short short8;            // bf16 frag
typedef __attribute__((ext_vector_type(8))) unsigned short ushort8v;
typedef __attribute__((ext_vector_type(4))) float floatx4;

__device__ __forceinline__ float siluf(float x) {
    return x / (1.f + __expf(-x));
}
__device__ __forceinline__ unsigned short f2bf(float f) {   // RNE, finite
    unsigned int u = __float_as_uint(f);
    return (unsigned short)((u + 0x7FFFu + ((u >> 16) & 1u)) >> 16);
}
__device__ __forceinline__ float bf2f(unsigned short u) {
    return __uint_as_float((unsigned int)u << 16);
}
__device__ __forceinline__ void gll16(const void* g, void* l) {
    __builtin_amdgcn_global_load_lds(
        (const __attribute__((address_space(1))) void*)g,
        (__attribute__((address_space(3))) void*)l, 16, 0, 0);
}

// ---------- fp32 -> bf16 cast, 8 elems/thread ----------
__global__ __launch_bounds__(256)
void cast_bf16_k(const float* __restrict__ in, unsigned short* __restrict__ out)
{
    size_t i = ((size_t)blockIdx.x * 256 + threadIdx.x) * 8;
    float4 a = *(const float4*)&in[i];
    float4 b = *(const float4*)&in[i + 4];
    ushort4 u0 = {f2bf(a.x), f2bf(a.y), f2bf(a.z), f2bf(a.w)};
    ushort4 u1 = {f2bf(b.x), f2bf(b.y), f2bf(b.z), f2bf(b.w)};
    *(ushort4*)&out[i] = u0;
    *(ushort4*)&out[i + 4] = u1;
}

// ---------- 256x256-tile 8-phase bf16 NT GEMM, grid-derived split-K --------
// M%256==0, N%256==0, K%128==0. grid = nsplit * (M/256)*(N/256);
// sk = blockIdx / tilesPerSplit; block computes C_partial[sk] over
// K-range [sk*K, (sk+1)*K). A/B row stride = lda. C partial stride M*ldc.
// Buffers: [2 kh][256 rows][32 shorts]; reads 10/2/10/2 per phase;
// 2 gll16/phase; vmcnt(6) once per K-tile.
#define MF16(acc_, a_, b_) \
    acc_ = __builtin_amdgcn_mfma_f32_16x16x32_bf16(a_, b_, acc_, 0, 0, 0)

#define PH_TOP()                                               \
    __builtin_amdgcn_s_barrier();                              \
    asm volatile("s_waitcnt lgkmcnt(0)" ::: "memory");         \
    __builtin_amdgcn_s_setprio(1);

#define PH_BOT()                                               \
    __builtin_amdgcn_s_setprio(0);                             \
    __builtin_amdgcn_s_barrier();

#define GROUP(LA, LB, S1, S2, S3, S4, VMTAIL)                                  \
    {                                                                          \
        short8 a0[8], a1[8], b0, b1, b2, b3;                                   \
        _Pragma("unroll")                                                      \
        for (int m = 0; m < 8; ++m)                                            \
            a0[m] = *(const short8*)&(LA)[aoff2 + (m << 9)];                   \
        b0 = *(const short8*)&(LB)[boff2];                                     \
        b1 = *(const short8*)&(LB)[boff2 + (1 << 9)];                          \
        S1;                                                                    \
        PH_TOP();                                                              \
        _Pragma("unroll")                                                      \
        for (int m = 0; m < 8; ++m) {                                          \
            MF16(acc[m][0], a0[m], b0);                                        \
            MF16(acc[m][1], a0[m], b1);                                        \
        }                                                                      \
        PH_BOT();                                                              \
        b2 = *(const short8*)&(LB)[boff2 + (2 << 9)];                          \
        b3 = *(const short8*)&(LB)[boff2 + (3 << 9)];                          \
        S2;                                                                    \
        PH_TOP();                                                              \
        _Pragma("unroll")                                                      \
        for (int m = 0; m < 8; ++m) {                                          \
            MF16(acc[m][2], a0[m], b2);                                        \
            MF16(acc[m][3], a0[m], b3);                                        \
        }                                                                      \
        PH_BOT();                                                              \
        _Pragma("unroll")                                                      \
        for (int m = 0; m < 8; ++m)                                            \
            a1[m] = *(const short8*)&(LA)[8192 + aoff2 + (m << 9)];            \
        b0 = *(const short8*)&(LB)[8192 + boff2];                              \
        b1 = *(const short8*)&(LB)[8192 + boff2 + (1 << 9)];                   \
        S3;                                                                    \
        PH_TOP();                                                              \
        _Pragma("unroll")                                                      \
        for (int m = 0; m < 8; ++m) {                                          \
            MF16(acc[m][0], a1[m], b0);                                        \
            MF16(acc[m][1], a1[m], b1);                                        \
        }                                                                      \
        PH_BOT();                                                              \
        b2 = *(const short8*)&(LB)[8192 + boff2 + (2 << 9)];                   \
        b3 = *(const short8*)&(LB)[8192 + boff2 + (3 << 9)];                   \
        S4;                                                                    \
        PH_TOP();                                                              \
        _Pragma("unroll")                                                      \
        for (int m = 0; m < 8; ++m) {                                          \
            MF16(acc[m][2], a1[m], b2);                                        \
            MF16(acc[m][3], a1[m], b3);                                        \
        }                                                                      \
        __builtin_amdgcn_s_setprio(0);                                         \
        VMTAIL;                                                                \
        __builtin_amdgcn_s_barrier();                                          \
    }

__global__ __launch_bounds__(512)
void gemm_bt_8ph(const unsigned short* __restrict__ A,
                 const unsigned short* __restrict__ B,
                 float* __restrict__ C, int M, int N, int K, int lda, int ldc)
{
    __shared__ __attribute__((aligned(16))) unsigned short A0s[16384];
    __shared__ __attribute__((aligned(16))) unsigned short B0s[16384];
    __shared__ __attribute__((aligned(16))) unsigned short A1s[16384];
    __shared__ __attribute__((aligned(16))) unsigned short B1s[16384];
    const int tid = threadIdx.x;
    const int lane = tid & 63, wave = tid >> 6;
    const int quad = lane >> 4, l15 = lane & 15;
    const int wm = wave >> 2, wn = wave & 3;

    // split-K decode + bijective XCD swizzle (m204) within the split.
    const int Mt = M >> 8, Nt = N >> 8;
    const int tps = Mt * Nt;
    const int sk = blockIdx.x / tps, inner = blockIdx.x % tps;
    const int q = tps >> 3, r = tps & 7;
    const int xcd = inner & 7, idx = inner >> 3;
    const int wgid = (xcd < r ? xcd * (q + 1) : r * (q + 1) + (xcd - r) * q) + idx;
    const int mt = wgid % Mt, nt = wgid / Mt;
    const int m0 = mt << 8, n0 = nt << 8;

    const unsigned short* Ab = A + (size_t)sk * K;
    const unsigned short* Bb = B + (size_t)sk * K;
    float* Cb = C + (size_t)sk * (size_t)M * ldc;

    // stage one 16KB K-half: phys chunk c holds logical k-chunk c^(row&3)
    // (pre-swizzled source, linear LDS dest).
    auto stA = [&](unsigned short* arr, int t, int kh) {
        const int kb = (t << 6) + (kh << 5);
#pragma unroll
        for (int i = 0; i < 2; ++i) {
            const int f = tid + (i << 9);
            const int rr = f >> 2, lc = (f & 3) ^ (rr & 3);
            gll16(&Ab[(size_t)(m0 + rr) * lda + kb + (lc << 3)],
                  &arr[(kh << 13) + ((size_t)f << 3)]);
        }
    };
    auto stB = [&](unsigned short* arr, int t, int kh) {
        const int kb = (t << 6) + (kh << 5);
#pragma unroll
        for (int i = 0; i < 2; ++i) {
            const int f = tid + (i << 9);
            const int rr = f >> 2, lc = (f & 3) ^ (rr & 3);
            gll16(&Bb[(size_t)(n0 + rr) * lda + kb + (lc << 3)],
                  &arr[(kh << 13) + ((size_t)f << 3)]);
        }
    };

    floatx4 acc[8][4] = {};

    const int ph = quad ^ (l15 & 3);                       // phys chunk on read
    const int aoff2 = ((wm << 7) + l15) * 32 + (ph << 3);  // shorts
    const int boff2 = ((wn << 6) + l15) * 32 + (ph << 3);

    // prologue: t0 full (8 gll) then t1 {Akh0,Bkh0,Akh1} (6 gll).
    stA(A0s, 0, 0); stB(B0s, 0, 0); stA(A0s, 0, 1); stB(B0s, 0, 1);
    stA(A1s, 1, 0); stB(B1s, 1, 0); stA(A1s, 1, 1);
    asm volatile("s_waitcnt vmcnt(6)" ::: "memory");
    __builtin_amdgcn_s_barrier();

    const int NITER = K >> 7;   // tile pairs
    for (int it = 0; it < NITER; ++it) {
        const int t = it << 1;
        const bool nl = (it + 1 < NITER);
        // group A: tile t (A0s,B0s)
        GROUP(A0s, B0s,
              stB(B1s, t + 1, 1),
              if (nl) stA(A0s, t + 2, 0),
              if (nl) stB(B0s, t + 2, 0),
              if (nl) stA(A0s, t + 2, 1),
              if (nl) asm volatile("s_waitcnt vmcnt(6)" ::: "memory");
              else    asm volatile("s_waitcnt vmcnt(0)" ::: "memory"))
        // group B: tile t+1 (A1s,B1s)
        GROUP(A1s, B1s,
              if (nl) stB(B0s, t + 2, 1),
              if (nl) stA(A1s, t + 3, 0),
              if (nl) stB(B1s, t + 3, 0),
              if (nl) stA(A1s, t + 3, 1),
              if (nl) asm volatile("s_waitcnt vmcnt(6)" ::: "memory");
              else    asm volatile("s_waitcnt vmcnt(0)" ::: "memory"))
    }

#pragma unroll
    for (int m = 0; m < 8; ++m) {
        const int row = m0 + (wm << 7) + m * 16 + (quad << 2);
#pragma unroll
        for (int n = 0; n < 4; ++n) {
            const int col = n0 + (wn << 6) + n * 16 + l15;
#pragma unroll
            for (int rr = 0; rr < 4; ++rr)
                Cb[(size_t)(row + rr) * ldc + col] = acc[m][n][rr];
        }
    }
}

// ---------- out split-K reduce: out = P0+P1+P2+P3 ----------
__global__ __launch_bounds__(256)
void out_reduce4_k(const float* __restrict__ P, float* __restrict__ out)
{
    const size_t i = ((size_t)blockIdx.x * 256 + threadIdx.x) * 4;
    const size_t stride = (size_t)kS * kHID;
    float4 s0 = *(const float4*)&P[i];
    float4 s1 = *(const float4*)&P[i + stride];
    float4 s2 = *(const float4*)&P[i + 2 * stride];
    float4 s3 = *(const float4*)&P[i + 3 * stride];
    float4 o;
    o.x = s0.x + s1.x + s2.x + s3.x;
    o.y = s0.y + s1.y + s2.y + s3.y;
    o.z = s0.z + s1.z + s2.z + s3.z;
    o.w = s0.w + s1.w + s2.w + s3.w;
    *(float4*)&out[i] = o;
}

// ---------- strip GEMM (cols 8192..8511), split-K=4 -> partials ----------
// grid: sk(4) x mt(16) x nt(3); B passed pre-offset to strip rows (320 rows).
__global__ __launch_bounds__(256)
void gemm_strip_sk(const unsigned short* __restrict__ A,
                   const unsigned short* __restrict__ B,
                   float* __restrict__ P, int K)
{
    __shared__ unsigned short As[128 * 64];
    __shared__ unsigned short Bs[128 * 64];
    const int bi = blockIdx.x;
    const int sk = bi / 48, rem = bi % 48, mt = rem / 3, nt = rem % 3;
    const int m0 = mt * 128, n0 = nt * 128, kbase = sk * 512;
    const int tid = threadIdx.x;
    const int lane = tid & 63, quad = lane >> 4, l15 = lane & 15;
    const int wave = tid >> 6;
    const int wm = (wave & 1) * 64, wn = (wave >> 1) * 64;

    floatx4 acc[4][4] = {};

    int rowS[4], lcS[4];
#pragma unroll
    for (int i = 0; i < 4; ++i) {
        int f = tid + 256 * i;
        rowS[i] = f >> 3;
        lcS[i] = ((f & 7) ^ (rowS[i] & 7)) * 8;
    }

    for (int kk = 0; kk < 512; kk += 64) {
        const int k0 = kbase + kk;
#pragma unroll
        for (int i = 0; i < 4; ++i) {
            int ra = m0 + rowS[i];
            gll16(&A[(size_t)ra * K + k0 + lcS[i]], &As[(size_t)(tid + 256 * i) * 8]);
        }
#pragma unroll
        for (int i = 0; i < 4; ++i) {
            int rb = n0 + rowS[i]; if (rb > 319) rb = 319;
            gll16(&B[(size_t)rb * K + k0 + lcS[i]], &Bs[(size_t)(tid + 256 * i) * 8]);
        }
        __syncthreads();

        short8 af[4][2], bf[4][2];
#pragma unroll
        for (int ks = 0; ks < 2; ++ks) {
            const int ph = ((ks * 4 + quad) ^ (l15 & 7)) * 8;
#pragma unroll
            for (int mi = 0; mi < 4; ++mi)
                af[mi][ks] = *(const short8*)&As[(size_t)(wm + mi * 16 + l15) * 64 + ph];
#pragma unroll
            for (int ni = 0; ni < 4; ++ni)
                bf[ni][ks] = *(const short8*)&Bs[(size_t)(wn + ni * 16 + l15) * 64 + ph];
        }
#pragma unroll
        for (int ks = 0; ks < 2; ++ks)
#pragma unroll
            for (int mi = 0; mi < 4; ++mi)
#pragma unroll
                for (int ni = 0; ni < 4; ++ni)
                    acc[mi][ni] = __builtin_amdgcn_mfma_f32_16x16x32_bf16(
                        af[mi][ks], bf[ni][ks], acc[mi][ni], 0, 0, 0);
        __syncthreads();
    }

    float* Po = P + (size_t)sk * kS * 320;
#pragma unroll
    for (int mi = 0; mi < 4; ++mi)
#pragma unroll
        for (int ni = 0; ni < 4; ++ni) {
            int col = n0 + wn + ni * 16 + l15;
            if (col < 320) {
#pragma unroll
                for (int r = 0; r < 4; ++r) {
                    int row = m0 + wm + mi * 16 + quad * 4 + r;
                    Po[(size_t)row * 320 + col] = acc[mi][ni][r];
                }
            }
        }
}

// ---------- strip reduce: proj[:,8192+n] = sum_sk P[sk] ----------
__global__ __launch_bounds__(256)
void strip_reduce_k(const float* __restrict__ P, float* __restrict__ proj)
{
    const size_t i = ((size_t)blockIdx.x * 256 + threadIdx.x) * 4;
    const size_t stride = (size_t)kS * 320;
    float4 s0 = *(const float4*)&P[i];
    float4 s1 = *(const float4*)&P[i + stride];
    float4 s2 = *(const float4*)&P[i + 2 * stride];
    float4 s3 = *(const float4*)&P[i + 3 * stride];
    float4 o;
    o.x = s0.x + s1.x + s2.x + s3.x;
    o.y = s0.y + s1.y + s2.y + s3.y;
    o.z = s0.z + s1.z + s2.z + s3.z;
    o.w = s0.w + s1.w + s2.w + s3.w;
    const int m = (int)(i / 320), n = (int)(i % 320);
    *(float4*)&proj[(size_t)m * kProj + 8192 + n] = o;
}

// ---------- conv+SiLU -> bf16 consumer layouts ----------
__global__ __launch_bounds__(256)
void conv_silu2_k(const float* __restrict__ proj, const float* __restrict__ cw,
                  const float* __restrict__ cb,
                  unsigned short* __restrict__ XT, unsigned short* __restrict__ Bg,
                  unsigned short* __restrict__ Btg, unsigned short* __restrict__ Cg)
{
    __shared__ __attribute__((aligned(16))) unsigned short T[64][264];
    const int bd = blockIdx.x % 68, bt = blockIdx.x / 68;
    const int d0 = bd * 64, t0 = bt * 256;
    const int tid = threadIdx.x;
    const int dl = tid & 63;
    const int d = d0 + dl;
    const float b0 = cb[d];
    const float w0 = cw[d * 4 + 0], w1 = cw[d * 4 + 1];
    const float w2 = cw[d * 4 + 2], w3 = cw[d * 4 + 3];
    for (int it = 0; it < 64; ++it) {
        int tl = it * 4 + (tid >> 6);
        int t = t0 + tl;
        const float* pc = &proj[(size_t)t * kProj + kI + d];
        float acc = b0 + w3 * pc[0];
        if (t >= 1) acc += w2 * pc[-(ptrdiff_t)kProj];
        if (t >= 2) acc += w1 * pc[-(ptrdiff_t)(2 * kProj)];
        if (t >= 3) acc += w0 * pc[-(ptrdiff_t)(3 * kProj)];
        T[dl][tl] = f2bf(siluf(acc));
    }
    __syncthreads();

    if (d0 < kI) {                       // X: XT[d][t], rows along t (coalesced)
        int row = tid >> 2, cg = (tid & 3) * 64;
#pragma unroll
        for (int j = 0; j < 8; ++j)
            *(ushort8v*)&XT[(size_t)(d0 + row) * kS + t0 + cg + j * 8] =
                *(const ushort8v*)&T[row][cg + j * 8];
    } else if (d0 < kI + kN) {           // B: Bt[n][t] + Bg[t][n]
        int n0 = d0 - kI;
        int row = tid >> 2, cg = (tid & 3) * 64;
#pragma unroll
        for (int j = 0; j < 8; ++j)
            *(ushort8v*)&Btg[(size_t)(n0 + row) * kS + t0 + cg + j * 8] =
                *(const ushort8v*)&T[row][cg + j * 8];
        for (int pass = 0; pass < 16; ++pass) {
            int tl = pass * 16 + (tid >> 4), nq = (tid & 15) * 4;
            ushort4 v = {T[nq][tl], T[nq + 1][tl], T[nq + 2][tl], T[nq + 3][tl]};
            *(ushort4*)&Bg[(size_t)(t0 + tl) * kN + n0 + nq] = v;
        }
    } else {                             // C: Cg[t][n]
        int n0 = d0 - (kI + kN);
        for (int pass = 0; pass < 16; ++pass) {
            int tl = pass * 16 + (tid >> 4), nq = (tid & 15) * 4;
            ushort4 v = {T[nq][tl], T[nq + 1][tl], T[nq + 2][tl], T[nq + 3][tl]};
            *(ushort4*)&Cg[(size_t)(t0 + tl) * kN + n0 + nq] = v;
        }
    }
}

// ---------- dt = softplus(proj_dt + bias); per-chunk cumsum(dt*A) ----------
__global__ __launch_bounds__(256)
void dt_cumsum_k(const float* __restrict__ proj, const float* __restrict__ dt_bias,
                 const float* __restrict__ A_log, float* __restrict__ dt,
                 float* __restrict__ acum)
{
    __shared__ float wsum[4];
    const int c = blockIdx.x >> 6, h = blockIdx.x & 63;
    const int l = threadIdx.x, t = c * kChunk + l;
    float a = -expf(A_log[h]);
    float z = proj[(size_t)t * kProj + kI + kConv + h] + dt_bias[h];
    float d = (z > 20.f) ? z : log1pf(expf(z));
    dt[t * kH + h] = d;
    float v = d * a;
    int lane = l & 63, w = l >> 6;
#pragma unroll
    for (int off = 1; off < 64; off <<= 1) {
        float u = __shfl_up(v, off);
        if (lane >= off) v += u;
    }
    if (lane == 63) wsum[w] = v;
    __syncthreads();
    float add = 0.f;
    for (int i = 0; i < w; ++i) add += wsum[i];
    acum[t * kH + h] = v + add;
}

// ---------- states (v2): bf16 MFMA. out[p][n] = sum_s Xw^T[p][s] Bt[n][s] ---
__global__ __launch_bounds__(256)
void states2_k(const unsigned short* __restrict__ XT,
               const unsigned short* __restrict__ Btg,
               const float* __restrict__ dt, const float* __restrict__ acum,
               float* __restrict__ states)
{
    __shared__ __attribute__((aligned(16))) unsigned short Aw[64 * 72];
    __shared__ __attribute__((aligned(16))) unsigned short Bs[128 * 64];
    __shared__ float Wl[256];
    const int c = blockIdx.x >> 6, h = blockIdx.x & 63;
    const int tid = threadIdx.x;
    const int wave = tid >> 6, lane = tid & 63;
    const int quad = lane >> 4, l15 = lane & 15;
    const float aend = acum[(size_t)(c * kChunk + 255) * kH + h];
    {
        int t = c * kChunk + tid;
        Wl[tid] = __expf(aend - acum[(size_t)t * kH + h]) * dt[(size_t)t * kH + h];
    }
    __syncthreads();

    floatx4 acc[4][2] = {};
    for (int lt = 0; lt < 4; ++lt) {
        const int s0 = c * kChunk + lt * 64;
#pragma unroll
        for (int i = 0; i < 2; ++i) {       // Aw[p][s] = XT * w, stride 72
            int f = tid + 256 * i;
            int p = f >> 3, sc = (f & 7) * 8;
            ushort8v xv = *(const ushort8v*)&XT[(size_t)(h * 64 + p) * kS + s0 + sc];
            ushort8v o;
#pragma unroll
            for (int j = 0; j < 8; ++j)
                o[j] = f2bf(bf2f(xv[j]) * Wl[lt * 64 + sc + j]);
            *(ushort8v*)&Aw[p * 72 + sc] = o;
        }
#pragma unroll
        for (int i = 0; i < 4; ++i) {       // Bs[n][s], phys chunk = lg ^ (n&7)
            int f = tid + 256 * i;
            int n = f >> 3, ph = f & 7, lg = ph ^ (n & 7);
            gll16(&Btg[(size_t)n * kS + s0 + lg * 8], &Bs[(size_t)f * 8]);
        }
        __syncthreads();
#pragma unroll
        for (int ks = 0; ks < 2; ++ks) {
            short8 bfr[2];
#pragma unroll
            for (int nj = 0; nj < 2; ++nj) {
                int n = (wave * 2 + nj) * 16 + l15;
                int ph = (ks * 4 + quad) ^ (n & 7);
                bfr[nj] = *(const short8*)&Bs[n * 64 + ph * 8];
            }
#pragma unroll
            for (int pi = 0; pi < 4; ++pi) {
                short8 af = *(const short8*)&Aw[(pi * 16 + l15) * 72 + ks * 32 + quad * 8];
                acc[pi][0] = __builtin_amdgcn_mfma_f32_16x16x32_bf16(af, bfr[0], acc[pi][0], 0, 0, 0);
                acc[pi][1] = __builtin_amdgcn_mfma_f32_16x16x32_bf16(af, bfr[1], acc[pi][1], 0, 0, 0);
            }
        }
        __syncthreads();
    }
    const size_t base = (size_t)(c * kH + h) * (kP * kN);
#pragma unroll
    for (int pi = 0; pi < 4; ++pi)
#pragma unroll
        for (int nj = 0; nj < 2; ++nj) {
            int n = (wave * 2 + nj) * 16 + l15;
#pragma unroll
            for (int r = 0; r < 4; ++r)
                states[base + (size_t)(pi * 16 + quad * 4 + r) * kN + n] = acc[pi][nj][r];
        }
}

// ---------- sequential inter-chunk recurrence ----------
__global__ __launch_bounds__(256)
void scan_k(const float* __restrict__ states, const float* __restrict__ acum,
            float* __restrict__ prev)
{
    const int h = blockIdx.x >> 3, seg = blockIdx.x & 7;
    const int e = (seg * 256 + threadIdx.x) * 4;
    float4 carry = make_float4(0.f, 0.f, 0.f, 0.f);
    for (int c = 0; c < kNC; ++c) {
        size_t base = (size_t)(c * kH + h) * (kP * kN);
        *(float4*)&prev[base + e] = carry;
        float dec = __expf(acum[(size_t)(c * kChunk + 255) * kH + h]);
        float4 st = *(const float4*)&states[base + e];
        carry.x = carry.x * dec + st.x; carry.y = carry.y * dec + st.y;
        carry.z = carry.z * dec + st.z; carry.w = carry.w * dec + st.w;
    }
}

// ---------- SSD Y (v4): gll16-staged bf16 tiles, XOR-swizzled ----------
__global__ __launch_bounds__(256)
void ssd_y4_k(const unsigned short* __restrict__ Cg,
              const unsigned short* __restrict__ Bg,
              const unsigned short* __restrict__ XT,
              const float* __restrict__ dt, const float* __restrict__ acum,
              const float* __restrict__ prev, const float* __restrict__ Dp,
              float* __restrict__ Y)
{
    __shared__ __attribute__((aligned(16))) unsigned short Cb[64 * 128];
    __shared__ __attribute__((aligned(16))) unsigned short Bb[64 * 128];
    __shared__ __attribute__((aligned(16))) unsigned short Xt[64 * 64];
    __shared__ __attribute__((aligned(16))) unsigned short Wb[64 * 72];
    __shared__ float At[64], Asv[64], Dtv[64];

    const int bi = blockIdx.x;
    const int ti = bi & 3, h = (bi >> 2) & 63, c = bi >> 8;
    const int tid = threadIdx.x;
    const int wave = tid >> 6, lane = tid & 63;
    const int quad = lane >> 4, l15 = lane & 15;
    const int trow0 = c * kChunk + ti * 64;
    const float Dh = Dp[h];

#pragma unroll
    for (int i = 0; i < 4; ++i) {
        int f = tid + 256 * i;
        int row = f >> 4, ph = f & 15, lg = ph ^ (row & 15);
        gll16(&Cg[(size_t)(trow0 + row) * kN + lg * 8], &Cb[(size_t)f * 8]);
    }
    const size_t pbase = (size_t)(c * kH + h) * (kP * kN);
#pragma unroll
    for (int r = 0; r < 8; ++r) {
        int f = tid + 256 * r;
        int row = f >> 5, c4 = (f & 31) * 4;          // 4 fp32 = half a 16B chunk
        float4 v = *(const float4*)&prev[pbase + (size_t)row * kN + c4];
        ushort4 u = {f2bf(v.x), f2bf(v.y), f2bf(v.z), f2bf(v.w)};
        int dst = row * 128 + ((((f & 31) >> 1) ^ (row & 15)) * 8) + (f & 1) * 4;
        *(ushort4*)&Bb[dst] = u;
    }
    if (tid < 64) At[tid] = acum[(size_t)(trow0 + tid) * kH + h];
    __syncthreads();

    floatx4 yacc[4] = {};
#pragma unroll
    for (int ks = 0; ks < 4; ++ks) {
        int cha = (ks * 4 + quad) ^ l15;
        short8 a = *(const short8*)&Cb[(wave * 16 + l15) * 128 + cha * 8];
#pragma unroll
        for (int ni = 0; ni < 4; ++ni) {
            short8 b = *(const short8*)&Bb[(ni * 16 + l15) * 128 + cha * 8];
            yacc[ni] = __builtin_amdgcn_mfma_f32_16x16x32_bf16(a, b, yacc[ni], 0, 0, 0);
        }
    }
    {
        float eAr[4];
#pragma unroll
        for (int r = 0; r < 4; ++r) eAr[r] = __expf(At[wave * 16 + quad * 4 + r]);
#pragma unroll
        for (int ni = 0; ni < 4; ++ni)
#pragma unroll
            for (int r = 0; r < 4; ++r) yacc[ni][r] *= eAr[r];
    }

    for (int si = 0; si <= ti; ++si) {
        const int srow0 = c * kChunk + si * 64;
        __syncthreads();
#pragma unroll
        for (int i = 0; i < 4; ++i) {       // B tile
            int f = tid + 256 * i;
            int row = f >> 4, ph = f & 15, lg = ph ^ (row & 15);
            gll16(&Bg[(size_t)(srow0 + row) * kN + lg * 8], &Bb[(size_t)f * 8]);
        }
#pragma unroll
        for (int i = 0; i < 2; ++i) {       // X^T tile [p][s]
            int f = tid + 256 * i;
            int p = f >> 3, ph = f & 7, lg = ph ^ (p & 7);
            gll16(&XT[(size_t)(h * 64 + p) * kS + srow0 + lg * 8], &Xt[(size_t)f * 8]);
        }
        if (tid < 64) {
            Asv[tid] = acum[(size_t)(srow0 + tid) * kH + h];
            Dtv[tid] = dt[(size_t)(srow0 + tid) * kH + h];
        }
        __syncthreads();

        floatx4 sacc[4] = {};
#pragma unroll
        for (int ks = 0; ks < 4; ++ks) {
            int cha = (ks * 4 + quad) ^ l15;
            short8 a = *(const short8*)&Cb[(wave * 16 + l15) * 128 + cha * 8];
#pragma unroll
            for (int ni = 0; ni < 4; ++ni) {
                short8 b = *(const short8*)&Bb[(ni * 16 + l15) * 128 + cha * 8];
                sacc[ni] = __builtin_amdgcn_mfma_f32_16x16x32_bf16(a, b, sacc[ni], 0, 0, 0);
            }
        }

        const bool diag = (si == ti);
#pragma unroll
        for (int ni = 0; ni < 4; ++ni) {
            int s_ = ni * 16 + l15;
            float as = Asv[s_], dts = Dtv[s_];
#pragma unroll
            for (int r = 0; r < 4; ++r) {
                int tl = wave * 16 + quad * 4 + r;
                float w = sacc[ni][r] * __expf(At[tl] - as) * dts;
                if (diag) {
                    if (s_ > tl) w = 0.f;
                    else if (s_ == tl) w += Dh;
                }
                Wb[tl * 72 + s_] = f2bf(w);
            }
        }
#pragma unroll
        for (int ks = 0; ks < 2; ++ks) {
            short8 aw = *(const short8*)&Wb[(wave * 16 + l15) * 72 + ks * 32 + quad * 8];
#pragma unroll
            for (int ni = 0; ni < 4; ++ni) {
                int ph = ((ks * 4 + quad) ^ (l15 & 7)) * 8;
                short8 xb = *(const short8*)&Xt[(ni * 16 + l15) * 64 + ph];
                yacc[ni] = __builtin_amdgcn_mfma_f32_16x16x32_bf16(aw, xb, yacc[ni], 0, 0, 0);
            }
        }
    }

#pragma unroll
    for (int ni = 0; ni < 4; ++ni)
#pragma unroll
        for (int r = 0; r < 4; ++r)
            Y[(size_t)(trow0 + wave * 16 + quad * 4 + r) * kI + h * kP + ni * 16 + l15]
                = yacc[ni][r];
}

// ---------- gated RMSNorm -> bf16 ----------
__global__ __launch_bounds__(256)
void rmsnorm_gate_k(const float* __restrict__ Y, const float* __restrict__ proj,
                    const float* __restrict__ nw, unsigned short* __restrict__ Yb)
{
    __shared__ float red[4];
    const int t = blockIdx.x, tid = threadIdx.x;
    const float* yrow = &Y[(size_t)t * kI];
    const float* grow = &proj[(size_t)t * kProj];
    float v[16];
    float ss = 0.f;
#pragma unroll
    for (int j = 0; j < 4; ++j) {
        int i = (tid + 256 * j) * 4;
        float4 y4 = *(const float4*)&yrow[i];
        float4 g4 = *(const float4*)&grow[i];
        float a = y4.x * siluf(g4.x), bq = y4.y * siluf(g4.y);
        float cq = y4.z * siluf(g4.z), d = y4.w * siluf(g4.w);
        v[j * 4 + 0] = a; v[j * 4 + 1] = bq; v[j * 4 + 2] = cq; v[j * 4 + 3] = d;
        ss += a * a + bq * bq + cq * cq + d * d;
    }
#pragma unroll
    for (int off = 32; off > 0; off >>= 1) ss += __shfl_down(ss, off);
    if ((tid & 63) == 0) red[tid >> 6] = ss;
    __syncthreads();
    float sum = red[0] + red[1] + red[2] + red[3];
    float rr = rsqrtf(sum * (1.f / kI) + kEps);
#pragma unroll
    for (int j = 0; j < 4; ++j) {
        int i = (tid + 256 * j) * 4;
        float4 w4 = *(const float4*)&nw[i];
        ushort4 o;
        o.x = f2bf(v[j * 4 + 0] * rr * w4.x);
        o.y = f2bf(v[j * 4 + 1] * rr * w4.y);
        o.z = f2bf(v[j * 4 + 2] * rr * w4.z);
        o.w = f2bf(v[j * 4 + 3] * rr * w4.w);
        *(ushort4*)&Yb[(size_t)t * kI + i] = o;
    }
}

extern "C" void kernel_launch(void* const* d_in, const int* in_sizes, int n_in,
                              void* d_out, int out_size, void* d_ws, size_t ws_size,
                              hipStream_t stream)
{
    const float* x       = (const float*)d_in[0];
    const float* W_in    = (const float*)d_in[1];
    const float* conv_w  = (const float*)d_in[2];
    const float* conv_b  = (const float*)d_in[3];
    const float* dt_bias = (const float*)d_in[4];
    const float* A_log   = (const float*)d_in[5];
    const float* Dp      = (const float*)d_in[6];
    const float* norm_w  = (const float*)d_in[7];
    const float* W_out   = (const float*)d_in[8];
    float* out = (float*)d_out;

    float* ws   = (float*)d_ws;
    float* proj = ws;                                       // 2048*8512 f
    unsigned short* XT  = (unsigned short*)(proj + (size_t)kS * kProj);  // 4096*2048
    unsigned short* Bg  = XT + (size_t)kI * kS;             // 2048*128
    unsigned short* Btg = Bg + (size_t)kS * kN;             // 128*2048
    unsigned short* Cg  = Btg + (size_t)kN * kS;            // 2048*128
    float* dtb  = (float*)(Cg + (size_t)kS * kN);           // 2048*64
    float* acum = dtb + (size_t)kS * kH;                    // 2048*64
    float* prev = acum + (size_t)kS * kH;                   // 4,194,304 f
    float* Y    = prev + (size_t)kNC * kH * kP * kN;        // 8,388,608 f
    float* states = Y;
    unsigned short* xb  = XT;                               // early alias
    unsigned short* Wb  = (unsigned short*)prev;            // early (spans into Y)
    unsigned short* Yb  = (unsigned short*)prev;            // late
    unsigned short* Wob = XT;                               // late
    // strip partials: after Wb's float-equivalent footprint; inside prev+Y.
    float* Pstrip = prev + ((size_t)kProj * kHID) / 2;
    // out-GEMM partials: proj region (dead after rmsnorm reads the gate);
    // needs 4*2048*2048 = 16.78M f <= 17.43M f.
    float* Pout = proj;

    dim3 blk(256);
    const int kNmain = 8192;               // 32 x 256-col tiles -> 256 blocks
    cast_bf16_k<<<(kS * kHID) / 2048, blk, 0, stream>>>(x, xb);
    cast_bf16_k<<<(kProj * kHID) / 2048, blk, 0, stream>>>(W_in, Wb);
    gemm_bt_8ph<<<(kS >> 8) * (kNmain >> 8), dim3(512), 0, stream>>>(
        xb, Wb, proj, kS, kNmain, kHID, kHID, kProj);
    gemm_strip_sk<<<192, blk, 0, stream>>>(
        xb, Wb + (size_t)kNmain * kHID, Pstrip, kHID);
    strip_reduce_k<<<(kS * 320) / 1024, blk, 0, stream>>>(Pstrip, proj);
    conv_silu2_k<<<68 * 8, blk, 0, stream>>>(proj, conv_w, conv_b, XT, Bg, Btg, Cg);
    dt_cumsum_k<<<kNC * kH, blk, 0, stream>>>(proj, dt_bias, A_log, dtb, acum);
    states2_k<<<kNC * kH, blk, 0, stream>>>(XT, Btg, dtb, acum, states);
    scan_k<<<kH * 8, blk, 0, stream>>>(states, acum, prev);
    ssd_y4_k<<<kNC * kH * 4, blk, 0, stream>>>(Cg, Bg, XT, dtb, acum, prev, Dp, Y);
    rmsnorm_gate_k<<<kS, blk, 0, stream>>>(Y, proj, norm_w, Yb);
    cast_bf16_k<<<(kHID * kI) / 2048, blk, 0, stream>>>(W_out, Wob);
    // out GEMM: 8-phase 256^2, split-K=4 (grid 4*64), K=1024 per block.
    gemm_bt_8ph<<<4 * (kS >> 8) * (kHID >> 8), dim3(512), 0, stream>>>(
        Yb, Wob, Pout, kS, kHID, kHID / 2, kI, kHID);
    out_reduce4_k<<<(kS * kHID) / 1024, blk, 0, stream>>>(Pout, out);
}

// Round 5
// 430.356 us; speedup vs baseline: 1.3668x; 1.0225x over previous
//
#include <hip/hip_runtime.h>
#include <math.h>

// Bamba-9B mixer, b=1 s=2048. Round 12: kill the 8ph LDS read bank conflict.
//  - Round-11 counters: SQ_LDS_BANK_CONFLICT = 6.29M = exactly 8 cyc per
//    ds_read_b128 in gemm_bt_8ph. The 64B-row K-half layout XOR'd the chunk
//    with row bits [1:0]; bank-group = (4*row+pc) mod 8 then covers only 4
//    groups per 8-lane beat -> 2-way conflict, LDS becomes the critical path
//    (matches MfmaUtil 33%).
//  - Fix: XOR with row bits [2:1] (write lc=(f&3)^((rr>>1)&3), read
//    ph=quad^((l15>>1)&3)) -> 8 consecutive rows hit all 8 bank groups.
//    Applies to both proj main and out GEMM (same kernel).
// Everything else unchanged from round 11.
static constexpr int kS     = 2048;
static constexpr int kHID   = 2048;
static constexpr int kI     = 4096;
static constexpr int kH     = 64;
static constexpr int kP     = 64;
static constexpr int kN     = 128;
static constexpr int kConv  = 4352;   // I + 2*G*N
static constexpr int kProj  = 8512;   // I + CONV + H
static constexpr int kChunk = 256;
static constexpr int kNC    = 8;
static constexpr float kEps = 1e-5f;

typedef __attribute__((ext_vector_type(8))) short short8;            // bf16 frag
typedef __attribute__((ext_vector_type(8))) unsigned short ushort8v;
typedef __attribute__((ext_vector_type(4))) float floatx4;

__device__ __forceinline__ float siluf(float x) {
    return x / (1.f + __expf(-x));
}
__device__ __forceinline__ unsigned short f2bf(float f) {   // RNE, finite
    unsigned int u = __float_as_uint(f);
    return (unsigned short)((u + 0x7FFFu + ((u >> 16) & 1u)) >> 16);
}
__device__ __forceinline__ float bf2f(unsigned short u) {
    return __uint_as_float((unsigned int)u << 16);
}
__device__ __forceinline__ void gll16(const void* g, void* l) {
    __builtin_amdgcn_global_load_lds(
        (const __attribute__((address_space(1))) void*)g,
        (__attribute__((address_space(3))) void*)l, 16, 0, 0);
}

// ---------- fp32 -> bf16 cast, 8 elems/thread ----------
__global__ __launch_bounds__(256)
void cast_bf16_k(const float* __restrict__ in, unsigned short* __restrict__ out)
{
    size_t i = ((size_t)blockIdx.x * 256 + threadIdx.x) * 8;
    float4 a = *(const float4*)&in[i];
    float4 b = *(const float4*)&in[i + 4];
    ushort4 u0 = {f2bf(a.x), f2bf(a.y), f2bf(a.z), f2bf(a.w)};
    ushort4 u1 = {f2bf(b.x), f2bf(b.y), f2bf(b.z), f2bf(b.w)};
    *(ushort4*)&out[i] = u0;
    *(ushort4*)&out[i + 4] = u1;
}

// ---------- 256x256-tile 8-phase bf16 NT GEMM, grid-derived split-K --------
// M%256==0, N%256==0, K%128==0. grid = nsplit * (M/256)*(N/256);
// sk = blockIdx / tilesPerSplit. Buffers: [2 kh][256 rows][32 shorts];
// reads 10/2/10/2 per phase; 2 gll16/phase; vmcnt(6) once per K-tile.
// Bank-conflict-free chunk swizzle: phys chunk pc holds logical chunk
// pc ^ ((row>>1)&3)  (row bits [2:1] -> 8 consecutive rows cover all 8
// 16B bank-groups of the 128B line pair).
#define MF16(acc_, a_, b_) \
    acc_ = __builtin_amdgcn_mfma_f32_16x16x32_bf16(a_, b_, acc_, 0, 0, 0)

#define PH_TOP()                                               \
    __builtin_amdgcn_s_barrier();                              \
    asm volatile("s_waitcnt lgkmcnt(0)" ::: "memory");         \
    __builtin_amdgcn_s_setprio(1);

#define PH_BOT()                                               \
    __builtin_amdgcn_s_setprio(0);                             \
    __builtin_amdgcn_s_barrier();

#define GROUP(LA, LB, S1, S2, S3, S4, VMTAIL)                                  \
    {                                                                          \
        short8 a0[8], a1[8], b0, b1, b2, b3;                                   \
        _Pragma("unroll")                                                      \
        for (int m = 0; m < 8; ++m)                                            \
            a0[m] = *(const short8*)&(LA)[aoff2 + (m << 9)];                   \
        b0 = *(const short8*)&(LB)[boff2];                                     \
        b1 = *(const short8*)&(LB)[boff2 + (1 << 9)];                          \
        S1;                                                                    \
        PH_TOP();                                                              \
        _Pragma("unroll")                                                      \
        for (int m = 0; m < 8; ++m) {                                          \
            MF16(acc[m][0], a0[m], b0);                                        \
            MF16(acc[m][1], a0[m], b1);                                        \
        }                                                                      \
        PH_BOT();                                                              \
        b2 = *(const short8*)&(LB)[boff2 + (2 << 9)];                          \
        b3 = *(const short8*)&(LB)[boff2 + (3 << 9)];                          \
        S2;                                                                    \
        PH_TOP();                                                              \
        _Pragma("unroll")                                                      \
        for (int m = 0; m < 8; ++m) {                                          \
            MF16(acc[m][2], a0[m], b2);                                        \
            MF16(acc[m][3], a0[m], b3);                                        \
        }                                                                      \
        PH_BOT();                                                              \
        _Pragma("unroll")                                                      \
        for (int m = 0; m < 8; ++m)                                            \
            a1[m] = *(const short8*)&(LA)[8192 + aoff2 + (m << 9)];            \
        b0 = *(const short8*)&(LB)[8192 + boff2];                              \
        b1 = *(const short8*)&(LB)[8192 + boff2 + (1 << 9)];                   \
        S3;                                                                    \
        PH_TOP();                                                              \
        _Pragma("unroll")                                                      \
        for (int m = 0; m < 8; ++m) {                                          \
            MF16(acc[m][0], a1[m], b0);                                        \
            MF16(acc[m][1], a1[m], b1);                                        \
        }                                                                      \
        PH_BOT();                                                              \
        b2 = *(const short8*)&(LB)[8192 + boff2 + (2 << 9)];                   \
        b3 = *(const short8*)&(LB)[8192 + boff2 + (3 << 9)];                   \
        S4;                                                                    \
        PH_TOP();                                                              \
        _Pragma("unroll")                                                      \
        for (int m = 0; m < 8; ++m) {                                          \
            MF16(acc[m][2], a1[m], b2);                                        \
            MF16(acc[m][3], a1[m], b3);                                        \
        }                                                                      \
        __builtin_amdgcn_s_setprio(0);                                         \
        VMTAIL;                                                                \
        __builtin_amdgcn_s_barrier();                                          \
    }

__global__ __launch_bounds__(512)
void gemm_bt_8ph(const unsigned short* __restrict__ A,
                 const unsigned short* __restrict__ B,
                 float* __restrict__ C, int M, int N, int K, int lda, int ldc)
{
    __shared__ __attribute__((aligned(16))) unsigned short A0s[16384];
    __shared__ __attribute__((aligned(16))) unsigned short B0s[16384];
    __shared__ __attribute__((aligned(16))) unsigned short A1s[16384];
    __shared__ __attribute__((aligned(16))) unsigned short B1s[16384];
    const int tid = threadIdx.x;
    const int lane = tid & 63, wave = tid >> 6;
    const int quad = lane >> 4, l15 = lane & 15;
    const int wm = wave >> 2, wn = wave & 3;

    // split-K decode + bijective XCD swizzle (m204) within the split.
    const int Mt = M >> 8, Nt = N >> 8;
    const int tps = Mt * Nt;
    const int sk = blockIdx.x / tps, inner = blockIdx.x % tps;
    const int q = tps >> 3, r = tps & 7;
    const int xcd = inner & 7, idx = inner >> 3;
    const int wgid = (xcd < r ? xcd * (q + 1) : r * (q + 1) + (xcd - r) * q) + idx;
    const int mt = wgid % Mt, nt = wgid / Mt;
    const int m0 = mt << 8, n0 = nt << 8;

    const unsigned short* Ab = A + (size_t)sk * K;
    const unsigned short* Bb = B + (size_t)sk * K;
    float* Cb = C + (size_t)sk * (size_t)M * ldc;

    // stage one 16KB K-half: phys chunk pc holds logical chunk pc^((rr>>1)&3)
    // (pre-swizzled source, linear LDS dest).
    auto stA = [&](unsigned short* arr, int t, int kh) {
        const int kb = (t << 6) + (kh << 5);
#pragma unroll
        for (int i = 0; i < 2; ++i) {
            const int f = tid + (i << 9);
            const int rr = f >> 2, lc = (f & 3) ^ ((rr >> 1) & 3);
            gll16(&Ab[(size_t)(m0 + rr) * lda + kb + (lc << 3)],
                  &arr[(kh << 13) + ((size_t)f << 3)]);
        }
    };
    auto stB = [&](unsigned short* arr, int t, int kh) {
        const int kb = (t << 6) + (kh << 5);
#pragma unroll
        for (int i = 0; i < 2; ++i) {
            const int f = tid + (i << 9);
            const int rr = f >> 2, lc = (f & 3) ^ ((rr >> 1) & 3);
            gll16(&Bb[(size_t)(n0 + rr) * lda + kb + (lc << 3)],
                  &arr[(kh << 13) + ((size_t)f << 3)]);
        }
    };

    floatx4 acc[8][4] = {};

    const int ph = quad ^ ((l15 >> 1) & 3);                // phys chunk on read
    const int aoff2 = ((wm << 7) + l15) * 32 + (ph << 3);  // shorts
    const int boff2 = ((wn << 6) + l15) * 32 + (ph << 3);

    // prologue: t0 full (8 gll) then t1 {Akh0,Bkh0,Akh1} (6 gll).
    stA(A0s, 0, 0); stB(B0s, 0, 0); stA(A0s, 0, 1); stB(B0s, 0, 1);
    stA(A1s, 1, 0); stB(B1s, 1, 0); stA(A1s, 1, 1);
    asm volatile("s_waitcnt vmcnt(6)" ::: "memory");
    __builtin_amdgcn_s_barrier();

    const int NITER = K >> 7;   // tile pairs
    for (int it = 0; it < NITER; ++it) {
        const int t = it << 1;
        const bool nl = (it + 1 < NITER);
        // group A: tile t (A0s,B0s)
        GROUP(A0s, B0s,
              stB(B1s, t + 1, 1),
              if (nl) stA(A0s, t + 2, 0),
              if (nl) stB(B0s, t + 2, 0),
              if (nl) stA(A0s, t + 2, 1),
              if (nl) asm volatile("s_waitcnt vmcnt(6)" ::: "memory");
              else    asm volatile("s_waitcnt vmcnt(0)" ::: "memory"))
        // group B: tile t+1 (A1s,B1s)
        GROUP(A1s, B1s,
              if (nl) stB(B0s, t + 2, 1),
              if (nl) stA(A1s, t + 3, 0),
              if (nl) stB(B1s, t + 3, 0),
              if (nl) stA(A1s, t + 3, 1),
              if (nl) asm volatile("s_waitcnt vmcnt(6)" ::: "memory");
              else    asm volatile("s_waitcnt vmcnt(0)" ::: "memory"))
    }

#pragma unroll
    for (int m = 0; m < 8; ++m) {
        const int row = m0 + (wm << 7) + m * 16 + (quad << 2);
#pragma unroll
        for (int n = 0; n < 4; ++n) {
            const int col = n0 + (wn << 6) + n * 16 + l15;
#pragma unroll
            for (int rr = 0; rr < 4; ++rr)
                Cb[(size_t)(row + rr) * ldc + col] = acc[m][n][rr];
        }
    }
}

// ---------- out split-K reduce: out = P0+P1+P2+P3 ----------
__global__ __launch_bounds__(256)
void out_reduce4_k(const float* __restrict__ P, float* __restrict__ out)
{
    const size_t i = ((size_t)blockIdx.x * 256 + threadIdx.x) * 4;
    const size_t stride = (size_t)kS * kHID;
    float4 s0 = *(const float4*)&P[i];
    float4 s1 = *(const float4*)&P[i + stride];
    float4 s2 = *(const float4*)&P[i + 2 * stride];
    float4 s3 = *(const float4*)&P[i + 3 * stride];
    float4 o;
    o.x = s0.x + s1.x + s2.x + s3.x;
    o.y = s0.y + s1.y + s2.y + s3.y;
    o.z = s0.z + s1.z + s2.z + s3.z;
    o.w = s0.w + s1.w + s2.w + s3.w;
    *(float4*)&out[i] = o;
}

// ---------- strip GEMM (cols 8192..8511), split-K=4 -> partials ----------
// grid: sk(4) x mt(16) x nt(3); B passed pre-offset to strip rows (320 rows).
__global__ __launch_bounds__(256)
void gemm_strip_sk(const unsigned short* __restrict__ A,
                   const unsigned short* __restrict__ B,
                   float* __restrict__ P, int K)
{
    __shared__ unsigned short As[128 * 64];
    __shared__ unsigned short Bs[128 * 64];
    const int bi = blockIdx.x;
    const int sk = bi / 48, rem = bi % 48, mt = rem / 3, nt = rem % 3;
    const int m0 = mt * 128, n0 = nt * 128, kbase = sk * 512;
    const int tid = threadIdx.x;
    const int lane = tid & 63, quad = lane >> 4, l15 = lane & 15;
    const int wave = tid >> 6;
    const int wm = (wave & 1) * 64, wn = (wave >> 1) * 64;

    floatx4 acc[4][4] = {};

    int rowS[4], lcS[4];
#pragma unroll
    for (int i = 0; i < 4; ++i) {
        int f = tid + 256 * i;
        rowS[i] = f >> 3;
        lcS[i] = ((f & 7) ^ (rowS[i] & 7)) * 8;
    }

    for (int kk = 0; kk < 512; kk += 64) {
        const int k0 = kbase + kk;
#pragma unroll
        for (int i = 0; i < 4; ++i) {
            int ra = m0 + rowS[i];
            gll16(&A[(size_t)ra * K + k0 + lcS[i]], &As[(size_t)(tid + 256 * i) * 8]);
        }
#pragma unroll
        for (int i = 0; i < 4; ++i) {
            int rb = n0 + rowS[i]; if (rb > 319) rb = 319;
            gll16(&B[(size_t)rb * K + k0 + lcS[i]], &Bs[(size_t)(tid + 256 * i) * 8]);
        }
        __syncthreads();

        short8 af[4][2], bf[4][2];
#pragma unroll
        for (int ks = 0; ks < 2; ++ks) {
            const int ph = ((ks * 4 + quad) ^ (l15 & 7)) * 8;
#pragma unroll
            for (int mi = 0; mi < 4; ++mi)
                af[mi][ks] = *(const short8*)&As[(size_t)(wm + mi * 16 + l15) * 64 + ph];
#pragma unroll
            for (int ni = 0; ni < 4; ++ni)
                bf[ni][ks] = *(const short8*)&Bs[(size_t)(wn + ni * 16 + l15) * 64 + ph];
        }
#pragma unroll
        for (int ks = 0; ks < 2; ++ks)
#pragma unroll
            for (int mi = 0; mi < 4; ++mi)
#pragma unroll
                for (int ni = 0; ni < 4; ++ni)
                    acc[mi][ni] = __builtin_amdgcn_mfma_f32_16x16x32_bf16(
                        af[mi][ks], bf[ni][ks], acc[mi][ni], 0, 0, 0);
        __syncthreads();
    }

    float* Po = P + (size_t)sk * kS * 320;
#pragma unroll
    for (int mi = 0; mi < 4; ++mi)
#pragma unroll
        for (int ni = 0; ni < 4; ++ni) {
            int col = n0 + wn + ni * 16 + l15;
            if (col < 320) {
#pragma unroll
                for (int r = 0; r < 4; ++r) {
                    int row = m0 + wm + mi * 16 + quad * 4 + r;
                    Po[(size_t)row * 320 + col] = acc[mi][ni][r];
                }
            }
        }
}

// ---------- strip reduce: proj[:,8192+n] = sum_sk P[sk] ----------
__global__ __launch_bounds__(256)
void strip_reduce_k(const float* __restrict__ P, float* __restrict__ proj)
{
    const size_t i = ((size_t)blockIdx.x * 256 + threadIdx.x) * 4;
    const size_t stride = (size_t)kS * 320;
    float4 s0 = *(const float4*)&P[i];
    float4 s1 = *(const float4*)&P[i + stride];
    float4 s2 = *(const float4*)&P[i + 2 * stride];
    float4 s3 = *(const float4*)&P[i + 3 * stride];
    float4 o;
    o.x = s0.x + s1.x + s2.x + s3.x;
    o.y = s0.y + s1.y + s2.y + s3.y;
    o.z = s0.z + s1.z + s2.z + s3.z;
    o.w = s0.w + s1.w + s2.w + s3.w;
    const int m = (int)(i / 320), n = (int)(i % 320);
    *(float4*)&proj[(size_t)m * kProj + 8192 + n] = o;
}

// ---------- conv+SiLU -> bf16 consumer layouts ----------
__global__ __launch_bounds__(256)
void conv_silu2_k(const float* __restrict__ proj, const float* __restrict__ cw,
                  const float* __restrict__ cb,
                  unsigned short* __restrict__ XT, unsigned short* __restrict__ Bg,
                  unsigned short* __restrict__ Btg, unsigned short* __restrict__ Cg)
{
    __shared__ __attribute__((aligned(16))) unsigned short T[64][264];
    const int bd = blockIdx.x % 68, bt = blockIdx.x / 68;
    const int d0 = bd * 64, t0 = bt * 256;
    const int tid = threadIdx.x;
    const int dl = tid & 63;
    const int d = d0 + dl;
    const float b0 = cb[d];
    const float w0 = cw[d * 4 + 0], w1 = cw[d * 4 + 1];
    const float w2 = cw[d * 4 + 2], w3 = cw[d * 4 + 3];
    for (int it = 0; it < 64; ++it) {
        int tl = it * 4 + (tid >> 6);
        int t = t0 + tl;
        const float* pc = &proj[(size_t)t * kProj + kI + d];
        float acc = b0 + w3 * pc[0];
        if (t >= 1) acc += w2 * pc[-(ptrdiff_t)kProj];
        if (t >= 2) acc += w1 * pc[-(ptrdiff_t)(2 * kProj)];
        if (t >= 3) acc += w0 * pc[-(ptrdiff_t)(3 * kProj)];
        T[dl][tl] = f2bf(siluf(acc));
    }
    __syncthreads();

    if (d0 < kI) {                       // X: XT[d][t], rows along t (coalesced)
        int row = tid >> 2, cg = (tid & 3) * 64;
#pragma unroll
        for (int j = 0; j < 8; ++j)
            *(ushort8v*)&XT[(size_t)(d0 + row) * kS + t0 + cg + j * 8] =
                *(const ushort8v*)&T[row][cg + j * 8];
    } else if (d0 < kI + kN) {           // B: Bt[n][t] + Bg[t][n]
        int n0 = d0 - kI;
        int row = tid >> 2, cg = (tid & 3) * 64;
#pragma unroll
        for (int j = 0; j < 8; ++j)
            *(ushort8v*)&Btg[(size_t)(n0 + row) * kS + t0 + cg + j * 8] =
                *(const ushort8v*)&T[row][cg + j * 8];
        for (int pass = 0; pass < 16; ++pass) {
            int tl = pass * 16 + (tid >> 4), nq = (tid & 15) * 4;
            ushort4 v = {T[nq][tl], T[nq + 1][tl], T[nq + 2][tl], T[nq + 3][tl]};
            *(ushort4*)&Bg[(size_t)(t0 + tl) * kN + n0 + nq] = v;
        }
    } else {                             // C: Cg[t][n]
        int n0 = d0 - (kI + kN);
        for (int pass = 0; pass < 16; ++pass) {
            int tl = pass * 16 + (tid >> 4), nq = (tid & 15) * 4;
            ushort4 v = {T[nq][tl], T[nq + 1][tl], T[nq + 2][tl], T[nq + 3][tl]};
            *(ushort4*)&Cg[(size_t)(t0 + tl) * kN + n0 + nq] = v;
        }
    }
}

// ---------- dt = softplus(proj_dt + bias); per-chunk cumsum(dt*A) ----------
__global__ __launch_bounds__(256)
void dt_cumsum_k(const float* __restrict__ proj, const float* __restrict__ dt_bias,
                 const float* __restrict__ A_log, float* __restrict__ dt,
                 float* __restrict__ acum)
{
    __shared__ float wsum[4];
    const int c = blockIdx.x >> 6, h = blockIdx.x & 63;
    const int l = threadIdx.x, t = c * kChunk + l;
    float a = -expf(A_log[h]);
    float z = proj[(size_t)t * kProj + kI + kConv + h] + dt_bias[h];
    float d = (z > 20.f) ? z : log1pf(expf(z));
    dt[t * kH + h] = d;
    float v = d * a;
    int lane = l & 63, w = l >> 6;
#pragma unroll
    for (int off = 1; off < 64; off <<= 1) {
        float u = __shfl_up(v, off);
        if (lane >= off) v += u;
    }
    if (lane == 63) wsum[w] = v;
    __syncthreads();
    float add = 0.f;
    for (int i = 0; i < w; ++i) add += wsum[i];
    acum[t * kH + h] = v + add;
}

// ---------- states (v2): bf16 MFMA. out[p][n] = sum_s Xw^T[p][s] Bt[n][s] ---
__global__ __launch_bounds__(256)
void states2_k(const unsigned short* __restrict__ XT,
               const unsigned short* __restrict__ Btg,
               const float* __restrict__ dt, const float* __restrict__ acum,
               float* __restrict__ states)
{
    __shared__ __attribute__((aligned(16))) unsigned short Aw[64 * 72];
    __shared__ __attribute__((aligned(16))) unsigned short Bs[128 * 64];
    __shared__ float Wl[256];
    const int c = blockIdx.x >> 6, h = blockIdx.x & 63;
    const int tid = threadIdx.x;
    const int wave = tid >> 6, lane = tid & 63;
    const int quad = lane >> 4, l15 = lane & 15;
    const float aend = acum[(size_t)(c * kChunk + 255) * kH + h];
    {
        int t = c * kChunk + tid;
        Wl[tid] = __expf(aend - acum[(size_t)t * kH + h]) * dt[(size_t)t * kH + h];
    }
    __syncthreads();

    floatx4 acc[4][2] = {};
    for (int lt = 0; lt < 4; ++lt) {
        const int s0 = c * kChunk + lt * 64;
#pragma unroll
        for (int i = 0; i < 2; ++i) {       // Aw[p][s] = XT * w, stride 72
            int f = tid + 256 * i;
            int p = f >> 3, sc = (f & 7) * 8;
            ushort8v xv = *(const ushort8v*)&XT[(size_t)(h * 64 + p) * kS + s0 + sc];
            ushort8v o;
#pragma unroll
            for (int j = 0; j < 8; ++j)
                o[j] = f2bf(bf2f(xv[j]) * Wl[lt * 64 + sc + j]);
            *(ushort8v*)&Aw[p * 72 + sc] = o;
        }
#pragma unroll
        for (int i = 0; i < 4; ++i) {       // Bs[n][s], phys chunk = lg ^ (n&7)
            int f = tid + 256 * i;
            int n = f >> 3, ph = f & 7, lg = ph ^ (n & 7);
            gll16(&Btg[(size_t)n * kS + s0 + lg * 8], &Bs[(size_t)f * 8]);
        }
        __syncthreads();
#pragma unroll
        for (int ks = 0; ks < 2; ++ks) {
            short8 bfr[2];
#pragma unroll
            for (int nj = 0; nj < 2; ++nj) {
                int n = (wave * 2 + nj) * 16 + l15;
                int ph = (ks * 4 + quad) ^ (n & 7);
                bfr[nj] = *(const short8*)&Bs[n * 64 + ph * 8];
            }
#pragma unroll
            for (int pi = 0; pi < 4; ++pi) {
                short8 af = *(const short8*)&Aw[(pi * 16 + l15) * 72 + ks * 32 + quad * 8];
                acc[pi][0] = __builtin_amdgcn_mfma_f32_16x16x32_bf16(af, bfr[0], acc[pi][0], 0, 0, 0);
                acc[pi][1] = __builtin_amdgcn_mfma_f32_16x16x32_bf16(af, bfr[1], acc[pi][1], 0, 0, 0);
            }
        }
        __syncthreads();
    }
    const size_t base = (size_t)(c * kH + h) * (kP * kN);
#pragma unroll
    for (int pi = 0; pi < 4; ++pi)
#pragma unroll
        for (int nj = 0; nj < 2; ++nj) {
            int n = (wave * 2 + nj) * 16 + l15;
#pragma unroll
            for (int r = 0; r < 4; ++r)
                states[base + (size_t)(pi * 16 + quad * 4 + r) * kN + n] = acc[pi][nj][r];
        }
}

// ---------- sequential inter-chunk recurrence ----------
__global__ __launch_bounds__(256)
void scan_k(const float* __restrict__ states, const float* __restrict__ acum,
            float* __restrict__ prev)
{
    const int h = blockIdx.x >> 3, seg = blockIdx.x & 7;
    const int e = (seg * 256 + threadIdx.x) * 4;
    float4 carry = make_float4(0.f, 0.f, 0.f, 0.f);
    for (int c = 0; c < kNC; ++c) {
        size_t base = (size_t)(c * kH + h) * (kP * kN);
        *(float4*)&prev[base + e] = carry;
        float dec = __expf(acum[(size_t)(c * kChunk + 255) * kH + h]);
        float4 st = *(const float4*)&states[base + e];
        carry.x = carry.x * dec + st.x; carry.y = carry.y * dec + st.y;
        carry.z = carry.z * dec + st.z; carry.w = carry.w * dec + st.w;
    }
}

// ---------- SSD Y (v4): gll16-staged bf16 tiles, XOR-swizzled ----------
__global__ __launch_bounds__(256)
void ssd_y4_k(const unsigned short* __restrict__ Cg,
              const unsigned short* __restrict__ Bg,
              const unsigned short* __restrict__ XT,
              const float* __restrict__ dt, const float* __restrict__ acum,
              const float* __restrict__ prev, const float* __restrict__ Dp,
              float* __restrict__ Y)
{
    __shared__ __attribute__((aligned(16))) unsigned short Cb[64 * 128];
    __shared__ __attribute__((aligned(16))) unsigned short Bb[64 * 128];
    __shared__ __attribute__((aligned(16))) unsigned short Xt[64 * 64];
    __shared__ __attribute__((aligned(16))) unsigned short Wb[64 * 72];
    __shared__ float At[64], Asv[64], Dtv[64];

    const int bi = blockIdx.x;
    const int ti = bi & 3, h = (bi >> 2) & 63, c = bi >> 8;
    const int tid = threadIdx.x;
    const int wave = tid >> 6, lane = tid & 63;
    const int quad = lane >> 4, l15 = lane & 15;
    const int trow0 = c * kChunk + ti * 64;
    const float Dh = Dp[h];

#pragma unroll
    for (int i = 0; i < 4; ++i) {
        int f = tid + 256 * i;
        int row = f >> 4, ph = f & 15, lg = ph ^ (row & 15);
        gll16(&Cg[(size_t)(trow0 + row) * kN + lg * 8], &Cb[(size_t)f * 8]);
    }
    const size_t pbase = (size_t)(c * kH + h) * (kP * kN);
#pragma unroll
    for (int r = 0; r < 8; ++r) {
        int f = tid + 256 * r;
        int row = f >> 5, c4 = (f & 31) * 4;          // 4 fp32 = half a 16B chunk
        float4 v = *(const float4*)&prev[pbase + (size_t)row * kN + c4];
        ushort4 u = {f2bf(v.x), f2bf(v.y), f2bf(v.z), f2bf(v.w)};
        int dst = row * 128 + ((((f & 31) >> 1) ^ (row & 15)) * 8) + (f & 1) * 4;
        *(ushort4*)&Bb[dst] = u;
    }
    if (tid < 64) At[tid] = acum[(size_t)(trow0 + tid) * kH + h];
    __syncthreads();

    floatx4 yacc[4] = {};
#pragma unroll
    for (int ks = 0; ks < 4; ++ks) {
        int cha = (ks * 4 + quad) ^ l15;
        short8 a = *(const short8*)&Cb[(wave * 16 + l15) * 128 + cha * 8];
#pragma unroll
        for (int ni = 0; ni < 4; ++ni) {
            short8 b = *(const short8*)&Bb[(ni * 16 + l15) * 128 + cha * 8];
            yacc[ni] = __builtin_amdgcn_mfma_f32_16x16x32_bf16(a, b, yacc[ni], 0, 0, 0);
        }
    }
    {
        float eAr[4];
#pragma unroll
        for (int r = 0; r < 4; ++r) eAr[r] = __expf(At[wave * 16 + quad * 4 + r]);
#pragma unroll
        for (int ni = 0; ni < 4; ++ni)
#pragma unroll
            for (int r = 0; r < 4; ++r) yacc[ni][r] *= eAr[r];
    }

    for (int si = 0; si <= ti; ++si) {
        const int srow0 = c * kChunk + si * 64;
        __syncthreads();
#pragma unroll
        for (int i = 0; i < 4; ++i) {       // B tile
            int f = tid + 256 * i;
            int row = f >> 4, ph = f & 15, lg = ph ^ (row & 15);
            gll16(&Bg[(size_t)(srow0 + row) * kN + lg * 8], &Bb[(size_t)f * 8]);
        }
#pragma unroll
        for (int i = 0; i < 2; ++i) {       // X^T tile [p][s]
            int f = tid + 256 * i;
            int p = f >> 3, ph = f & 7, lg = ph ^ (p & 7);
            gll16(&XT[(size_t)(h * 64 + p) * kS + srow0 + lg * 8], &Xt[(size_t)f * 8]);
        }
        if (tid < 64) {
            Asv[tid] = acum[(size_t)(srow0 + tid) * kH + h];
            Dtv[tid] = dt[(size_t)(srow0 + tid) * kH + h];
        }
        __syncthreads();

        floatx4 sacc[4] = {};
#pragma unroll
        for (int ks = 0; ks < 4; ++ks) {
            int cha = (ks * 4 + quad) ^ l15;
            short8 a = *(const short8*)&Cb[(wave * 16 + l15) * 128 + cha * 8];
#pragma unroll
            for (int ni = 0; ni < 4; ++ni) {
                short8 b = *(const short8*)&Bb[(ni * 16 + l15) * 128 + cha * 8];
                sacc[ni] = __builtin_amdgcn_mfma_f32_16x16x32_bf16(a, b, sacc[ni], 0, 0, 0);
            }
        }

        const bool diag = (si == ti);
#pragma unroll
        for (int ni = 0; ni < 4; ++ni) {
            int s_ = ni * 16 + l15;
            float as = Asv[s_], dts = Dtv[s_];
#pragma unroll
            for (int r = 0; r < 4; ++r) {
                int tl = wave * 16 + quad * 4 + r;
                float w = sacc[ni][r] * __expf(At[tl] - as) * dts;
                if (diag) {
                    if (s_ > tl) w = 0.f;
                    else if (s_ == tl) w += Dh;
                }
                Wb[tl * 72 + s_] = f2bf(w);
            }
        }
#pragma unroll
        for (int ks = 0; ks < 2; ++ks) {
            short8 aw = *(const short8*)&Wb[(wave * 16 + l15) * 72 + ks * 32 + quad * 8];
#pragma unroll
            for (int ni = 0; ni < 4; ++ni) {
                int ph = ((ks * 4 + quad) ^ (l15 & 7)) * 8;
                short8 xb = *(const short8*)&Xt[(ni * 16 + l15) * 64 + ph];
                yacc[ni] = __builtin_amdgcn_mfma_f32_16x16x32_bf16(aw, xb, yacc[ni], 0, 0, 0);
            }
        }
    }

#pragma unroll
    for (int ni = 0; ni < 4; ++ni)
#pragma unroll
        for (int r = 0; r < 4; ++r)
            Y[(size_t)(trow0 + wave * 16 + quad * 4 + r) * kI + h * kP + ni * 16 + l15]
                = yacc[ni][r];
}

// ---------- gated RMSNorm -> bf16 ----------
__global__ __launch_bounds__(256)
void rmsnorm_gate_k(const float* __restrict__ Y, const float* __restrict__ proj,
                    const float* __restrict__ nw, unsigned short* __restrict__ Yb)
{
    __shared__ float red[4];
    const int t = blockIdx.x, tid = threadIdx.x;
    const float* yrow = &Y[(size_t)t * kI];
    const float* grow = &proj[(size_t)t * kProj];
    float v[16];
    float ss = 0.f;
#pragma unroll
    for (int j = 0; j < 4; ++j) {
        int i = (tid + 256 * j) * 4;
        float4 y4 = *(const float4*)&yrow[i];
        float4 g4 = *(const float4*)&grow[i];
        float a = y4.x * siluf(g4.x), bq = y4.y * siluf(g4.y);
        float cq = y4.z * siluf(g4.z), d = y4.w * siluf(g4.w);
        v[j * 4 + 0] = a; v[j * 4 + 1] = bq; v[j * 4 + 2] = cq; v[j * 4 + 3] = d;
        ss += a * a + bq * bq + cq * cq + d * d;
    }
#pragma unroll
    for (int off = 32; off > 0; off >>= 1) ss += __shfl_down(ss, off);
    if ((tid & 63) == 0) red[tid >> 6] = ss;
    __syncthreads();
    float sum = red[0] + red[1] + red[2] + red[3];
    float rr = rsqrtf(sum * (1.f / kI) + kEps);
#pragma unroll
    for (int j = 0; j < 4; ++j) {
        int i = (tid + 256 * j) * 4;
        float4 w4 = *(const float4*)&nw[i];
        ushort4 o;
        o.x = f2bf(v[j * 4 + 0] * rr * w4.x);
        o.y = f2bf(v[j * 4 + 1] * rr * w4.y);
        o.z = f2bf(v[j * 4 + 2] * rr * w4.z);
        o.w = f2bf(v[j * 4 + 3] * rr * w4.w);
        *(ushort4*)&Yb[(size_t)t * kI + i] = o;
    }
}

extern "C" void kernel_launch(void* const* d_in, const int* in_sizes, int n_in,
                              void* d_out, int out_size, void* d_ws, size_t ws_size,
                              hipStream_t stream)
{
    const float* x       = (const float*)d_in[0];
    const float* W_in    = (const float*)d_in[1];
    const float* conv_w  = (const float*)d_in[2];
    const float* conv_b  = (const float*)d_in[3];
    const float* dt_bias = (const float*)d_in[4];
    const float* A_log   = (const float*)d_in[5];
    const float* Dp      = (const float*)d_in[6];
    const float* norm_w  = (const float*)d_in[7];
    const float* W_out   = (const float*)d_in[8];
    float* out = (float*)d_out;

    float* ws   = (float*)d_ws;
    float* proj = ws;                                       // 2048*8512 f
    unsigned short* XT  = (unsigned short*)(proj + (size_t)kS * kProj);  // 4096*2048
    unsigned short* Bg  = XT + (size_t)kI * kS;             // 2048*128
    unsigned short* Btg = Bg + (size_t)kS * kN;             // 128*2048
    unsigned short* Cg  = Btg + (size_t)kN * kS;            // 2048*128
    float* dtb  = (float*)(Cg + (size_t)kS * kN);           // 2048*64
    float* acum = dtb + (size_t)kS * kH;                    // 2048*64
    float* prev = acum + (size_t)kS * kH;                   // 4,194,304 f
    float* Y    = prev + (size_t)kNC * kH * kP * kN;        // 8,388,608 f
    float* states = Y;
    unsigned short* xb  = XT;                               // early alias
    unsigned short* Wb  = (unsigned short*)prev;            // early (spans into Y)
    unsigned short* Yb  = (unsigned short*)prev;            // late
    unsigned short* Wob = XT;                               // late
    // strip partials: after Wb's float-equivalent footprint; inside prev+Y.
    float* Pstrip = prev + ((size_t)kProj * kHID) / 2;
    // out-GEMM partials: proj region (dead after rmsnorm reads the gate);
    // needs 4*2048*2048 = 16.78M f <= 17.43M f.
    float* Pout = proj;

    dim3 blk(256);
    const int kNmain = 8192;               // 32 x 256-col tiles -> 256 blocks
    cast_bf16_k<<<(kS * kHID) / 2048, blk, 0, stream>>>(x, xb);
    cast_bf16_k<<<(kProj * kHID) / 2048, blk, 0, stream>>>(W_in, Wb);
    gemm_bt_8ph<<<(kS >> 8) * (kNmain >> 8), dim3(512), 0, stream>>>(
        xb, Wb, proj, kS, kNmain, kHID, kHID, kProj);
    gemm_strip_sk<<<192, blk, 0, stream>>>(
        xb, Wb + (size_t)kNmain * kHID, Pstrip, kHID);
    strip_reduce_k<<<(kS * 320) / 1024, blk, 0, stream>>>(Pstrip, proj);
    conv_silu2_k<<<68 * 8, blk, 0, stream>>>(proj, conv_w, conv_b, XT, Bg, Btg, Cg);
    dt_cumsum_k<<<kNC * kH, blk, 0, stream>>>(proj, dt_bias, A_log, dtb, acum);
    states2_k<<<kNC * kH, blk, 0, stream>>>(XT, Btg, dtb, acum, states);
    scan_k<<<kH * 8, blk, 0, stream>>>(states, acum, prev);
    ssd_y4_k<<<kNC * kH * 4, blk, 0, stream>>>(Cg, Bg, XT, dtb, acum, prev, Dp, Y);
    rmsnorm_gate_k<<<kS, blk, 0, stream>>>(Y, proj, norm_w, Yb);
    cast_bf16_k<<<(kHID * kI) / 2048, blk, 0, stream>>>(W_out, Wob);
    // out GEMM: 8-phase 256^2, split-K=4 (grid 4*64), K=1024 per block.
    gemm_bt_8ph<<<4 * (kS >> 8) * (kHID >> 8), dim3(512), 0, stream>>>(
        Yb, Wob, Pout, kS, kHID, kHID / 2, kI, kHID);
    out_reduce4_k<<<(kS * kHID) / 1024, blk, 0, stream>>>(Pout, out);
}